// Round 1
// baseline (411.570 us; speedup 1.0000x reference)
//
#include <hip/hip_runtime.h>
#include <cstddef>

#define BN 2
#define CH 48
#define HW 4096
#define NH 3
#define CPH 16
#define QC 144      // 3*CH
#define RR 3        // CH/16
#define KSPLIT 8
#define PSTR 17     // 16 acc + 1 denom

// ---- workspace layout (floats) ----
constexpr size_t N_XN  = (size_t)BN*CH*HW;        // 393216
constexpr size_t N_TOK = (size_t)BN*NH*HW*CPH;    // 393216
constexpr size_t N_QKV = (size_t)BN*QC*HW;        // 1179648
constexpr size_t OFF_XN = 0;
constexpr size_t OFF_QN = OFF_XN + N_XN;
constexpr size_t OFF_KN = OFF_QN + N_TOK;
constexpr size_t OFF_VT = OFF_KN + N_TOK;
constexpr size_t OFF_Y1 = OFF_VT + N_TOK;
constexpr size_t OFF_BP = OFF_Y1 + N_XN;          // 32 blocks * 48
constexpr size_t OFF_SE = OFF_BP + 32*CH;
constexpr size_t OFF_SH = OFF_SE + BN*CH + 32;    // shared region (qkv1/qkv2, later part)
constexpr size_t OFF_QKV1 = OFF_SH;
constexpr size_t OFF_QKV2 = OFF_SH + N_QKV;
constexpr size_t OFF_PART = OFF_SH;               // aliases qkv1/qkv2 after prep

// ---------- K1: LayerNorm over C (per pixel) + per-block pool partials ----------
__global__ __launch_bounds__(256) void k_ln1(const float* __restrict__ x,
                                             const float* __restrict__ lw,
                                             const float* __restrict__ lb,
                                             float* __restrict__ xn,
                                             float* __restrict__ bpool) {
  __shared__ float wsum[4][CH];
  int p = blockIdx.x*256 + threadIdx.x;   // 0..8191
  int b = p >> 12, hw = p & 4095;
  const float* xp = x + (size_t)b*CH*HW + hw;
  float v[CH]; float s = 0.f, ss = 0.f;
#pragma unroll
  for (int c = 0; c < CH; ++c) { float t = xp[(size_t)c*HW]; v[c] = t; s += t; ss += t*t; }
  float mu = s * (1.f/CH);
  float var = ss * (1.f/CH) - mu*mu;
  float rs = rsqrtf(var + 1e-6f);
  float* xnp = xn + (size_t)b*CH*HW + hw;
  int lane = threadIdx.x & 63, wid = threadIdx.x >> 6;
#pragma unroll
  for (int c = 0; c < CH; ++c) {
    float t = lw[c] * ((v[c]-mu)*rs) + lb[c];
    v[c] = t;
    xnp[(size_t)c*HW] = t;
  }
#pragma unroll
  for (int c = 0; c < CH; ++c) {
    float r = v[c];
    r += __shfl_xor(r,32); r += __shfl_xor(r,16); r += __shfl_xor(r,8);
    r += __shfl_xor(r,4);  r += __shfl_xor(r,2);  r += __shfl_xor(r,1);
    if (lane == 0) wsum[wid][c] = r;
  }
  __syncthreads();
  if (threadIdx.x < CH) {
    float a = wsum[0][threadIdx.x] + wsum[1][threadIdx.x] + wsum[2][threadIdx.x] + wsum[3][threadIdx.x];
    bpool[(size_t)blockIdx.x*CH + threadIdx.x] = a;
  }
}

// ---------- K2: SE MLP (pool mean -> relu fc -> sigmoid fc) ----------
__global__ void k_se(const float* __restrict__ bpool,
                     const float* __restrict__ w1, const float* __restrict__ b1,
                     const float* __restrict__ w2, const float* __restrict__ b2,
                     float* __restrict__ se) {
  __shared__ float pm[BN*CH];
  __shared__ float yr[BN*RR];
  int t = threadIdx.x;
  if (t < BN*CH) {
    int b = t / CH, c = t % CH;
    float a = 0.f;
    for (int i = 0; i < 16; ++i) a += bpool[(size_t)(b*16+i)*CH + c];
    pm[t] = a * (1.f/HW);
  }
  __syncthreads();
  if (t < BN*RR) {
    int b = t / RR, r = t % RR;
    float a = b1[r];
    for (int c = 0; c < CH; ++c) a += w1[r*CH+c] * pm[b*CH+c];
    yr[t] = fmaxf(a, 0.f);
  }
  __syncthreads();
  if (t < BN*CH) {
    int b = t / CH, c = t % CH;
    float a = b2[c];
    for (int r = 0; r < RR; ++r) a += w2[c*RR+r] * yr[b*RR+r];
    se[t] = 1.f / (1.f + __expf(-a));
  }
}

// ---------- K3: conv1x1 48 -> 144 ----------
__global__ __launch_bounds__(256) void k_conv1(const float* __restrict__ xn,
                                               const float* __restrict__ w,
                                               const float* __restrict__ bias,
                                               float* __restrict__ out) {
  int blk = blockIdx.x;               // b*QC + o
  int b = blk / QC, o = blk % QC;
  const float* wrow = w + (size_t)o*CH;
  const float* xb = xn + (size_t)b*CH*HW;
  float bo = bias[o];
  float* op = out + (size_t)blk*HW;
  for (int p = threadIdx.x; p < HW; p += 256) {
    float a = bo;
#pragma unroll
    for (int c = 0; c < CH; ++c) a += wrow[c] * xb[(size_t)c*HW + p];
    op[p] = a;
  }
}

// ---------- K4: depthwise 3x3 SAME ----------
__global__ __launch_bounds__(256) void k_dw(const float* __restrict__ in,
                                            const float* __restrict__ w,
                                            const float* __restrict__ bias,
                                            float* __restrict__ out) {
  int idx = blockIdx.x*256 + threadIdx.x;     // B*QC*HW
  int p = idx & 4095;
  int ch = (idx >> 12) % QC;
  int b  = idx / (QC*HW);
  int y = p >> 6, xc = p & 63;
  const float* ip = in + ((size_t)b*QC + ch)*HW;
  const float* wc = w + (size_t)ch*9;
  float a = bias[ch];
#pragma unroll
  for (int dy = 0; dy < 3; ++dy) {
    int yy = y + dy - 1;
    if (yy < 0 || yy >= 64) continue;
#pragma unroll
    for (int dx = 0; dx < 3; ++dx) {
      int xx = xc + dx - 1;
      if (xx < 0 || xx >= 64) continue;
      a += wc[dy*3+dx] * ip[yy*64 + xx];
    }
  }
  out[idx] = a;
}

// ---------- K5: token transpose + l2norm(q,k), fold temp into q ----------
__global__ __launch_bounds__(256) void k_prep(const float* __restrict__ qkv,
                                              const float* __restrict__ temp,
                                              float* __restrict__ qn,
                                              float* __restrict__ kn,
                                              float* __restrict__ vt) {
  int t = blockIdx.x*256 + threadIdx.x;   // bh*HW + n
  int n = t & 4095; int bh = t >> 12;
  int b = bh / NH, h = bh % NH;
  const float* base = qkv + (size_t)b*QC*HW + n;
  float q[16], k[16], v[16];
  float sq = 0.f, sk = 0.f;
#pragma unroll
  for (int cc = 0; cc < 16; ++cc) {
    float qv = base[(size_t)(      h*16+cc)*HW];
    float kv = base[(size_t)( 48 + h*16+cc)*HW];
    float vv = base[(size_t)( 96 + h*16+cc)*HW];
    q[cc] = qv; k[cc] = kv; v[cc] = vv;
    sq += qv*qv; sk += kv*kv;
  }
  float tq = temp[h] / fmaxf(sqrtf(sq), 1e-12f);
  float ik = 1.f    / fmaxf(sqrtf(sk), 1e-12f);
  float4* qp = (float4*)(qn + (size_t)t*16);
  float4* kp = (float4*)(kn + (size_t)t*16);
  float4* vp = (float4*)(vt + (size_t)t*16);
#pragma unroll
  for (int i = 0; i < 4; ++i) {
    qp[i] = make_float4(q[4*i]*tq, q[4*i+1]*tq, q[4*i+2]*tq, q[4*i+3]*tq);
    kp[i] = make_float4(k[4*i]*ik, k[4*i+1]*ik, k[4*i+2]*ik, k[4*i+3]*ik);
    vp[i] = make_float4(v[4*i],    v[4*i+1],    v[4*i+2],    v[4*i+3]);
  }
}

// ---------- K6: flash attention partials (no max needed: args in [0,temp]) ----------
__global__ __launch_bounds__(128) void k_attn(const float* __restrict__ qn,
                                              const float* __restrict__ kn,
                                              const float* __restrict__ vt,
                                              float* __restrict__ part) {
  int blk = blockIdx.x;                 // bh(6) x qt(32) x ks(8)
  int ks = blk & (KSPLIT-1);
  int qt = (blk >> 3) & 31;
  int bh = blk >> 8;
  int q = qt*128 + threadIdx.x;
  const float4* qp = (const float4*)(qn + ((size_t)bh*HW + q)*16);
  float4 q0 = qp[0], q1 = qp[1], q2 = qp[2], q3 = qp[3];
  float a0=0,a1=0,a2=0,a3=0,a4=0,a5=0,a6=0,a7=0,a8=0,a9=0,a10=0,a11=0,a12=0,a13=0,a14=0,a15=0;
  float den = 0.f;
  const float4* Kb = (const float4*)(kn + (size_t)bh*HW*16);
  const float4* Vb = (const float4*)(vt + (size_t)bh*HW*16);
  int kbeg = ks * (HW/KSPLIT);
  int kend = kbeg + (HW/KSPLIT);
  for (int k = kbeg; k < kend; ++k) {
    float4 ka = Kb[(size_t)4*k+0], kb = Kb[(size_t)4*k+1], kc = Kb[(size_t)4*k+2], kd = Kb[(size_t)4*k+3];
    float s0 = q0.x*ka.x + q0.y*ka.y + q0.z*ka.z + q0.w*ka.w;
    float s1 = q1.x*kb.x + q1.y*kb.y + q1.z*kb.z + q1.w*kb.w;
    float s2 = q2.x*kc.x + q2.y*kc.y + q2.z*kc.z + q2.w*kc.w;
    float s3 = q3.x*kd.x + q3.y*kd.y + q3.z*kd.z + q3.w*kd.w;
    float s = (s0+s1) + (s2+s3);
    float wgt = __expf(fmaxf(s, 0.f));
    den += wgt;
    float4 va = Vb[(size_t)4*k+0], vb = Vb[(size_t)4*k+1], vc = Vb[(size_t)4*k+2], vd = Vb[(size_t)4*k+3];
    a0  += wgt*va.x; a1  += wgt*va.y; a2  += wgt*va.z; a3  += wgt*va.w;
    a4  += wgt*vb.x; a5  += wgt*vb.y; a6  += wgt*vb.z; a7  += wgt*vb.w;
    a8  += wgt*vc.x; a9  += wgt*vc.y; a10 += wgt*vc.z; a11 += wgt*vc.w;
    a12 += wgt*vd.x; a13 += wgt*vd.y; a14 += wgt*vd.z; a15 += wgt*vd.w;
  }
  float* pp = part + ((size_t)(ks*6 + bh)*HW + q)*PSTR;
  pp[0]=a0;  pp[1]=a1;  pp[2]=a2;  pp[3]=a3;
  pp[4]=a4;  pp[5]=a5;  pp[6]=a6;  pp[7]=a7;
  pp[8]=a8;  pp[9]=a9;  pp[10]=a10; pp[11]=a11;
  pp[12]=a12; pp[13]=a13; pp[14]=a14; pp[15]=a15;
  pp[16]=den;
}

// ---------- K7: combine ksplits + y1 = x + xn*se*beta + attn*beta2 ----------
__global__ __launch_bounds__(256) void k_comb(const float* __restrict__ part,
                                              const float* __restrict__ x,
                                              const float* __restrict__ xn,
                                              const float* __restrict__ se,
                                              const float* __restrict__ beta,
                                              const float* __restrict__ beta2,
                                              float* __restrict__ y1) {
  int t = blockIdx.x*256 + threadIdx.x;    // bh*HW + n
  int n = t & 4095; int bh = t >> 12;
  int b = bh / NH, h = bh % NH;
  float acc[16] = {0,0,0,0,0,0,0,0,0,0,0,0,0,0,0,0};
  float den = 0.f;
  for (int ks = 0; ks < KSPLIT; ++ks) {
    const float* pp = part + ((size_t)(ks*6 + bh)*HW + n)*PSTR;
#pragma unroll
    for (int i = 0; i < 16; ++i) acc[i] += pp[i];
    den += pp[16];
  }
  float inv = 1.f / den;
#pragma unroll
  for (int cc = 0; cc < 16; ++cc) {
    int c = h*16 + cc;
    size_t idx = ((size_t)b*CH + c)*HW + n;
    y1[idx] = x[idx] + xn[idx]*se[b*CH+c]*beta[c] + acc[cc]*inv*beta2[c];
  }
}

// ---------- K8: LN2 + gated conv FFN fused, final output ----------
__global__ __launch_bounds__(128) void k_ffn(const float* __restrict__ y1,
                                             const float* __restrict__ lw,
                                             const float* __restrict__ lb,
                                             const float* __restrict__ w4,
                                             const float* __restrict__ b4,
                                             const float* __restrict__ w5,
                                             const float* __restrict__ b5,
                                             const float* __restrict__ gamma,
                                             float* __restrict__ out) {
  __shared__ float w5t[CH*CH];   // transposed: w5t[o*CH+oo] = w5[oo*CH+o]
  for (int i = threadIdx.x; i < CH*CH; i += 128) {
    int oo = i / CH, o = i % CH;
    w5t[o*CH + oo] = w5[i];
  }
  __syncthreads();
  int p = blockIdx.x*128 + threadIdx.x;   // 8192 pixels
  int b = p >> 12, n = p & 4095;
  const float* yp = y1 + (size_t)b*CH*HW + n;
  float t[CH]; float s = 0.f, ss = 0.f;
#pragma unroll
  for (int c = 0; c < CH; ++c) { float v = yp[(size_t)c*HW]; t[c] = v; s += v; ss += v*v; }
  float mu = s * (1.f/CH);
  float rs = rsqrtf(ss*(1.f/CH) - mu*mu + 1e-6f);
#pragma unroll
  for (int c = 0; c < CH; ++c) t[c] = lw[c]*((t[c]-mu)*rs) + lb[c];
  float outa[CH];
#pragma unroll
  for (int o = 0; o < CH; ++o) outa[o] = b5[o];
#pragma unroll 4
  for (int o = 0; o < CH; ++o) {          // runtime loop; weights via uniform (scalar) loads
    float f1 = b4[o], f2 = b4[o+CH];
#pragma unroll
    for (int c = 0; c < CH; ++c) {
      f1 += t[c] * w4[(size_t)o*CH + c];
      f2 += t[c] * w4[(size_t)(o+CH)*CH + c];
    }
    float g = f1 * f2;
#pragma unroll
    for (int oo4 = 0; oo4 < CH/4; ++oo4) {
      float4 wv = *(const float4*)&w5t[o*CH + oo4*4];
      outa[oo4*4+0] += g*wv.x; outa[oo4*4+1] += g*wv.y;
      outa[oo4*4+2] += g*wv.z; outa[oo4*4+3] += g*wv.w;
    }
  }
  float* op = out + (size_t)b*CH*HW + n;
#pragma unroll
  for (int o = 0; o < CH; ++o) op[(size_t)o*HW] = yp[(size_t)o*HW] + outa[o]*gamma[o];
}

extern "C" void kernel_launch(void* const* d_in, const int* in_sizes, int n_in,
                              void* d_out, int out_size, void* d_ws, size_t ws_size,
                              hipStream_t stream) {
  const float* x      = (const float*)d_in[0];
  const float* ln1_w  = (const float*)d_in[1];
  const float* ln1_b  = (const float*)d_in[2];
  const float* qkv_w  = (const float*)d_in[3];
  const float* qkv_b  = (const float*)d_in[4];
  const float* dw_w   = (const float*)d_in[5];
  const float* dw_b   = (const float*)d_in[6];
  const float* temp   = (const float*)d_in[7];
  const float* ca_w1  = (const float*)d_in[8];
  const float* ca_b1  = (const float*)d_in[9];
  const float* ca_w2  = (const float*)d_in[10];
  const float* ca_b2  = (const float*)d_in[11];
  const float* beta   = (const float*)d_in[12];
  const float* beta2  = (const float*)d_in[13];
  const float* ln2_w  = (const float*)d_in[14];
  const float* ln2_b  = (const float*)d_in[15];
  const float* conv4_w= (const float*)d_in[16];
  const float* conv4_b= (const float*)d_in[17];
  const float* conv5_w= (const float*)d_in[18];
  const float* conv5_b= (const float*)d_in[19];
  const float* gamma  = (const float*)d_in[20];

  float* ws   = (float*)d_ws;
  float* xn   = ws + OFF_XN;
  float* qn   = ws + OFF_QN;
  float* kn   = ws + OFF_KN;
  float* vt   = ws + OFF_VT;
  float* y1   = ws + OFF_Y1;
  float* bp   = ws + OFF_BP;
  float* se   = ws + OFF_SE;
  float* qkv1 = ws + OFF_QKV1;
  float* qkv2 = ws + OFF_QKV2;
  float* part = ws + OFF_PART;
  float* out  = (float*)d_out;

  k_ln1<<<32, 256, 0, stream>>>(x, ln1_w, ln1_b, xn, bp);
  k_se<<<1, 128, 0, stream>>>(bp, ca_w1, ca_b1, ca_w2, ca_b2, se);
  k_conv1<<<BN*QC, 256, 0, stream>>>(xn, qkv_w, qkv_b, qkv1);
  k_dw<<<BN*QC*HW/256, 256, 0, stream>>>(qkv1, dw_w, dw_b, qkv2);
  k_prep<<<BN*NH*HW/256, 256, 0, stream>>>(qkv2, temp, qn, kn, vt);
  k_attn<<<6*32*KSPLIT, 128, 0, stream>>>(qn, kn, vt, part);
  k_comb<<<BN*NH*HW/256, 256, 0, stream>>>(part, x, xn, se, beta, beta2, y1);
  k_ffn<<<64, 128, 0, stream>>>(y1, ln2_w, ln2_b, conv4_w, conv4_b, conv5_w, conv5_b, gamma, out);
}

// Round 2
// 178.007 us; speedup vs baseline: 2.3121x; 2.3121x over previous
//
#include <hip/hip_runtime.h>
#include <cstddef>

#define BN 2
#define CH 48
#define HW 4096
#define NH 3
#define CPH 16
#define QC 144      // 3*CH
#define RR 3        // CH/16
#define KSPLIT 4
#define PSTR 17     // 16 acc + 1 denom

typedef __attribute__((ext_vector_type(8))) short bf16x8;
typedef __attribute__((ext_vector_type(16))) float f32x16;
typedef __attribute__((ext_vector_type(4))) float f32x4;

// ---- workspace layout (floats) ----
constexpr size_t N_XN  = (size_t)BN*CH*HW;        // 393216
constexpr size_t N_QKV = (size_t)BN*QC*HW;        // 1179648
constexpr size_t N_BF  = (size_t)BN*NH*HW*16/2;   // 98304 f32 slots for bf16 [bh][n][16]
constexpr size_t OFF_XN = 0;
constexpr size_t OFF_Y1 = OFF_XN + N_XN;
constexpr size_t OFF_BP = OFF_Y1 + N_XN;          // 32*CH
constexpr size_t OFF_SE = OFF_BP + 2048;
constexpr size_t OFF_QB = OFF_SE + 128;
constexpr size_t OFF_KB = OFF_QB + N_BF;
constexpr size_t OFF_VT = OFF_KB + N_BF;
constexpr size_t OFF_BIG  = OFF_VT + N_BF;
constexpr size_t OFF_QKV1 = OFF_BIG;
constexpr size_t OFF_QKV2 = OFF_BIG + N_QKV;
constexpr size_t OFF_PART = OFF_BIG;              // 4*6*4096*17 = 1671168 <= 2*N_QKV
constexpr size_t OFF_TN   = OFF_BIG;              // after part consumed
constexpr size_t OFF_G    = OFF_BIG + N_XN;

static __device__ __forceinline__ unsigned pkbf(float a, float b) {
  unsigned ua = __float_as_uint(a), ub = __float_as_uint(b);
  ua = (ua + 0x7fffu + ((ua >> 16) & 1u)) >> 16;
  ub = (ub + 0x7fffu + ((ub >> 16) & 1u)) >> 16;
  return ua | (ub << 16);
}

// ---------- K1: LayerNorm over C (per pixel) + per-block pool partials ----------
__global__ __launch_bounds__(256) void k_ln1(const float* __restrict__ x,
                                             const float* __restrict__ lw,
                                             const float* __restrict__ lb,
                                             float* __restrict__ xn,
                                             float* __restrict__ bpool) {
  __shared__ float wsum[4][CH];
  int p = blockIdx.x*256 + threadIdx.x;
  int b = p >> 12, hw = p & 4095;
  const float* xp = x + (size_t)b*CH*HW + hw;
  float v[CH]; float s = 0.f, ss = 0.f;
#pragma unroll
  for (int c = 0; c < CH; ++c) { float t = xp[(size_t)c*HW]; v[c] = t; s += t; ss += t*t; }
  float mu = s * (1.f/CH);
  float var = ss * (1.f/CH) - mu*mu;
  float rs = rsqrtf(var + 1e-6f);
  float* xnp = xn + (size_t)b*CH*HW + hw;
  int lane = threadIdx.x & 63, wid = threadIdx.x >> 6;
#pragma unroll
  for (int c = 0; c < CH; ++c) {
    float t = lw[c] * ((v[c]-mu)*rs) + lb[c];
    v[c] = t;
    xnp[(size_t)c*HW] = t;
  }
#pragma unroll
  for (int c = 0; c < CH; ++c) {
    float r = v[c];
    r += __shfl_xor(r,32); r += __shfl_xor(r,16); r += __shfl_xor(r,8);
    r += __shfl_xor(r,4);  r += __shfl_xor(r,2);  r += __shfl_xor(r,1);
    if (lane == 0) wsum[wid][c] = r;
  }
  __syncthreads();
  if (threadIdx.x < CH) {
    float a = wsum[0][threadIdx.x] + wsum[1][threadIdx.x] + wsum[2][threadIdx.x] + wsum[3][threadIdx.x];
    bpool[(size_t)blockIdx.x*CH + threadIdx.x] = a;
  }
}

// ---------- K2: SE MLP ----------
__global__ void k_se(const float* __restrict__ bpool,
                     const float* __restrict__ w1, const float* __restrict__ b1,
                     const float* __restrict__ w2, const float* __restrict__ b2,
                     float* __restrict__ se) {
  __shared__ float pm[BN*CH];
  __shared__ float yr[BN*RR];
  int t = threadIdx.x;
  if (t < BN*CH) {
    int b = t / CH, c = t % CH;
    float a = 0.f;
    for (int i = 0; i < 16; ++i) a += bpool[(size_t)(b*16+i)*CH + c];
    pm[t] = a * (1.f/HW);
  }
  __syncthreads();
  if (t < BN*RR) {
    int b = t / RR, r = t % RR;
    float a = b1[r];
    for (int c = 0; c < CH; ++c) a += w1[r*CH+c] * pm[b*CH+c];
    yr[t] = fmaxf(a, 0.f);
  }
  __syncthreads();
  if (t < BN*CH) {
    int b = t / CH, c = t % CH;
    float a = b2[c];
    for (int r = 0; r < RR; ++r) a += w2[c*RR+r] * yr[b*RR+r];
    se[t] = 1.f / (1.f + __expf(-a));
  }
}

// ---------- K3: conv1x1 48 -> 144, 4 out-channels per block ----------
__global__ __launch_bounds__(256) void k_conv1(const float* __restrict__ xn,
                                               const float* __restrict__ w,
                                               const float* __restrict__ bias,
                                               float* __restrict__ out) {
  int blk = blockIdx.x;               // b(2) x og(36) x strip(4)
  int strip = blk & 3;
  int og = (blk >> 2) % 36;
  int b = blk / 144;
  int o = og * 4;
  const float* xb = xn + (size_t)b*CH*HW;
  float b0 = bias[o], b1 = bias[o+1], b2 = bias[o+2], b3 = bias[o+3];
  for (int p = strip*1024 + threadIdx.x; p < strip*1024 + 1024; p += 256) {
    float a0 = b0, a1 = b1, a2 = b2, a3 = b3;
#pragma unroll
    for (int c = 0; c < CH; ++c) {
      float xv = xb[(size_t)c*HW + p];
      a0 += w[(size_t)o*CH + c]     * xv;
      a1 += w[(size_t)(o+1)*CH + c] * xv;
      a2 += w[(size_t)(o+2)*CH + c] * xv;
      a3 += w[(size_t)(o+3)*CH + c] * xv;
    }
    out[((size_t)b*QC + o)*HW + p]     = a0;
    out[((size_t)b*QC + o + 1)*HW + p] = a1;
    out[((size_t)b*QC + o + 2)*HW + p] = a2;
    out[((size_t)b*QC + o + 3)*HW + p] = a3;
  }
}

// ---------- K4: depthwise 3x3 SAME ----------
__global__ __launch_bounds__(256) void k_dw(const float* __restrict__ in,
                                            const float* __restrict__ w,
                                            const float* __restrict__ bias,
                                            float* __restrict__ out) {
  int idx = blockIdx.x*256 + threadIdx.x;
  int p = idx & 4095;
  int ch = (idx >> 12) % QC;
  int b  = idx / (QC*HW);
  int y = p >> 6, xc = p & 63;
  const float* ip = in + ((size_t)b*QC + ch)*HW;
  const float* wc = w + (size_t)ch*9;
  float a = bias[ch];
#pragma unroll
  for (int dy = 0; dy < 3; ++dy) {
    int yy = y + dy - 1;
    if (yy < 0 || yy >= 64) continue;
#pragma unroll
    for (int dx = 0; dx < 3; ++dx) {
      int xx = xc + dx - 1;
      if (xx < 0 || xx >= 64) continue;
      a += wc[dy*3+dx] * ip[yy*64 + xx];
    }
  }
  out[idx] = a;
}

// ---------- K5: token transpose + l2norm(q,k) -> bf16; V transposed bf16 ----------
__global__ __launch_bounds__(256) void k_prep(const float* __restrict__ qkv,
                                              const float* __restrict__ temp,
                                              ushort* __restrict__ Qb,
                                              ushort* __restrict__ Kb,
                                              ushort* __restrict__ Vtb) {
  int t = blockIdx.x*256 + threadIdx.x;   // bh*HW + n
  int n = t & 4095; int bh = t >> 12;
  int b = bh / NH, h = bh % NH;
  const float* base = qkv + (size_t)b*QC*HW + n;
  float q[16], k[16], v[16];
  float sq = 0.f, sk = 0.f;
#pragma unroll
  for (int cc = 0; cc < 16; ++cc) {
    float qv = base[(size_t)(      h*16+cc)*HW];
    float kv = base[(size_t)( 48 + h*16+cc)*HW];
    float vv = base[(size_t)( 96 + h*16+cc)*HW];
    q[cc] = qv; k[cc] = kv; v[cc] = vv;
    sq += qv*qv; sk += kv*kv;
  }
  float tq = temp[h] / fmaxf(sqrtf(sq), 1e-12f);
  float ik = 1.f    / fmaxf(sqrtf(sk), 1e-12f);
  uint qp[8], kp[8];
#pragma unroll
  for (int i = 0; i < 8; ++i) {
    qp[i] = pkbf(q[2*i]*tq, q[2*i+1]*tq);
    kp[i] = pkbf(k[2*i]*ik, k[2*i+1]*ik);
  }
  uint4* qo = (uint4*)(Qb + (size_t)t*16);
  uint4* ko = (uint4*)(Kb + (size_t)t*16);
  qo[0] = make_uint4(qp[0],qp[1],qp[2],qp[3]);
  qo[1] = make_uint4(qp[4],qp[5],qp[6],qp[7]);
  ko[0] = make_uint4(kp[0],kp[1],kp[2],kp[3]);
  ko[1] = make_uint4(kp[4],kp[5],kp[6],kp[7]);
#pragma unroll
  for (int cc = 0; cc < 16; ++cc)
    Vtb[((size_t)bh*16 + cc)*HW + n] = (ushort)(pkbf(v[cc], 0.f) & 0xffffu);
}

// ---------- K6: MFMA flash attention partials ----------
// S^T = K.Q^T via mfma_32x32x16 (K-dim=16=cph); per-lane softmax (keys lane-local);
// P repacked via wave-private swizzled LDS; PV via mfma_16x16x32 (K=32 keys).
__global__ __launch_bounds__(256) void k_attn(const ushort* __restrict__ Qb,
                                              const ushort* __restrict__ Kb,
                                              const ushort* __restrict__ Vtb,
                                              float* __restrict__ part) {
  __shared__ ushort plds[4][32][32];   // [wave][q][key] bf16, 64B rows, swizzled 16B units
  __shared__ float dens[4][32];
  int blk = blockIdx.x;                // bh(6) x qt(32) x ks(4)
  int ks = blk & (KSPLIT-1);
  int qt = (blk >> 2) & 31;
  int bh = blk >> 7;
  int lane = threadIdx.x & 63;
  int wid  = threadIdx.x >> 6;
  int l31 = lane & 31;
  int lhi = lane >> 5;                 // 0/1
  int qbase = qt*128 + wid*32;

  // persistent Q fragment (B-operand of swapped QK^T): Q[q=l31][ch=8*lhi..+7]
  bf16x8 qf = *(const bf16x8*)(Qb + ((size_t)bh*HW + qbase + l31)*16 + lhi*8);

  const f32x16 z16 = {0,0,0,0,0,0,0,0,0,0,0,0,0,0,0,0};
  f32x4 acc0 = {0,0,0,0}, acc1 = {0,0,0,0};
  float den = 0.f;
  char* prow = (char*)&plds[wid][0][0];
  int qr = lane & 15, gr = lane >> 4;
  int rdoff0 = qr*64 + 16*(gr ^ ((qr>>1)&3));

  int kbeg = ks * (HW/KSPLIT);
  for (int kk = kbeg; kk < kbeg + HW/KSPLIT; kk += 32) {
    // K fragment (A-operand): K[key=l31][ch=8*lhi..+7]
    bf16x8 kf = *(const bf16x8*)(Kb + ((size_t)bh*HW + kk + l31)*16 + lhi*8);
    f32x16 st = __builtin_amdgcn_mfma_f32_32x32x16_bf16(kf, qf, z16, 0, 0, 0);
    // st reg r: key = (r&3) + 8*(r>>2) + 4*lhi (chunk-local), q = l31
    int sw = (l31 >> 1) & 3;
#pragma unroll
    for (int g4 = 0; g4 < 4; ++g4) {
      float e0 = __expf(fmaxf(st[4*g4+0], 0.f));
      float e1 = __expf(fmaxf(st[4*g4+1], 0.f));
      float e2 = __expf(fmaxf(st[4*g4+2], 0.f));
      float e3 = __expf(fmaxf(st[4*g4+3], 0.f));
      den += (e0+e1) + (e2+e3);
      uint2 pk;
      pk.x = pkbf(e0, e1);
      pk.y = pkbf(e2, e3);
      *(uint2*)(prow + l31*64 + 16*(g4 ^ sw) + 8*lhi) = pk;
    }
    // V fragment (B-operand of PV): Vt[ch=lane&15][key = kk + 8*gr .. +7]
    bf16x8 vf = *(const bf16x8*)(Vtb + ((size_t)bh*16 + qr)*HW + kk + 8*gr);
    // P fragments (A-operand): P[q][key 8*gr..+7], swizzled read (2-way, free)
    bf16x8 pa0 = *(const bf16x8*)(prow + rdoff0);
    bf16x8 pa1 = *(const bf16x8*)(prow + 1024 + rdoff0);
    acc0 = __builtin_amdgcn_mfma_f32_16x16x32_bf16(pa0, vf, acc0, 0, 0, 0);
    acc1 = __builtin_amdgcn_mfma_f32_16x16x32_bf16(pa1, vf, acc1, 0, 0, 0);
  }

  // combine den over the two key-halves (lanes l and l^32 hold same q)
  den += __shfl_xor(den, 32);
  size_t pb = (size_t)(ks*6 + bh)*HW;
  int rbase = qbase + (gr << 2);
#pragma unroll
  for (int r = 0; r < 4; ++r) {
    part[(pb + rbase + r)*PSTR + qr]      = acc0[r];
    part[(pb + rbase + 16 + r)*PSTR + qr] = acc1[r];
  }
  if (lane < 32) part[(pb + qbase + lane)*PSTR + 16] = den;
  (void)dens;
}

// ---------- K7: combine ksplits + y1 = x + xn*se*beta + attn*beta2 ----------
__global__ __launch_bounds__(256) void k_comb(const float* __restrict__ part,
                                              const float* __restrict__ x,
                                              const float* __restrict__ xn,
                                              const float* __restrict__ se,
                                              const float* __restrict__ beta,
                                              const float* __restrict__ beta2,
                                              float* __restrict__ y1) {
  int t = blockIdx.x*256 + threadIdx.x;    // bh*HW + n
  int n = t & 4095; int bh = t >> 12;
  int b = bh / NH, h = bh % NH;
  float acc[16] = {0,0,0,0,0,0,0,0,0,0,0,0,0,0,0,0};
  float den = 0.f;
  for (int ks = 0; ks < KSPLIT; ++ks) {
    const float* pp = part + ((size_t)(ks*6 + bh)*HW + n)*PSTR;
#pragma unroll
    for (int i = 0; i < 16; ++i) acc[i] += pp[i];
    den += pp[16];
  }
  float inv = 1.f / den;
#pragma unroll
  for (int cc = 0; cc < 16; ++cc) {
    int c = h*16 + cc;
    size_t idx = ((size_t)b*CH + c)*HW + n;
    y1[idx] = x[idx] + xn[idx]*se[b*CH+c]*beta[c] + acc[cc]*inv*beta2[c];
  }
}

// ---------- K8a: LN2 per pixel ----------
__global__ __launch_bounds__(256) void k_ln2(const float* __restrict__ y1,
                                             const float* __restrict__ lw,
                                             const float* __restrict__ lb,
                                             float* __restrict__ tn) {
  int p = blockIdx.x*256 + threadIdx.x;
  int b = p >> 12, n = p & 4095;
  const float* yp = y1 + (size_t)b*CH*HW + n;
  float t[CH]; float s = 0.f, ss = 0.f;
#pragma unroll
  for (int c = 0; c < CH; ++c) { float v = yp[(size_t)c*HW]; t[c] = v; s += v; ss += v*v; }
  float mu = s * (1.f/CH);
  float rs = rsqrtf(ss*(1.f/CH) - mu*mu + 1e-6f);
  float* tp = tn + (size_t)b*CH*HW + n;
#pragma unroll
  for (int c = 0; c < CH; ++c) tp[(size_t)c*HW] = lw[c]*((t[c]-mu)*rs) + lb[c];
}

// ---------- K8b: conv4 + gate ----------
__global__ __launch_bounds__(256) void k_gate(const float* __restrict__ tn,
                                              const float* __restrict__ w4,
                                              const float* __restrict__ b4,
                                              float* __restrict__ g) {
  int blk = blockIdx.x;              // b(2) x o(48) x strip(4)
  int strip = blk & 3;
  int o = (blk >> 2) % CH;
  int b = blk / (CH*4);
  const float* w1 = w4 + (size_t)o*CH;
  const float* w2 = w4 + (size_t)(o+CH)*CH;
  const float* tb = tn + (size_t)b*CH*HW;
  float bb1 = b4[o], bb2 = b4[o+CH];
  float* gp = g + ((size_t)b*CH + o)*HW;
  for (int p = strip*1024 + threadIdx.x; p < strip*1024 + 1024; p += 256) {
    float f1 = bb1, f2 = bb2;
#pragma unroll
    for (int c = 0; c < CH; ++c) {
      float xv = tb[(size_t)c*HW + p];
      f1 += w1[c]*xv; f2 += w2[c]*xv;
    }
    gp[p] = f1*f2;
  }
}

// ---------- K8c: conv5 + residual ----------
__global__ __launch_bounds__(256) void k_conv5(const float* __restrict__ g,
                                               const float* __restrict__ w5,
                                               const float* __restrict__ b5,
                                               const float* __restrict__ gamma,
                                               const float* __restrict__ y1,
                                               float* __restrict__ out) {
  int blk = blockIdx.x;              // b(2) x o(48) x strip(4)
  int strip = blk & 3;
  int o = (blk >> 2) % CH;
  int b = blk / (CH*4);
  const float* wrow = w5 + (size_t)o*CH;
  const float* gb = g + (size_t)b*CH*HW;
  float bo = b5[o], gm = gamma[o];
  const float* yp = y1 + ((size_t)b*CH + o)*HW;
  float* op = out + ((size_t)b*CH + o)*HW;
  for (int p = strip*1024 + threadIdx.x; p < strip*1024 + 1024; p += 256) {
    float a = bo;
#pragma unroll
    for (int c = 0; c < CH; ++c) a += wrow[c] * gb[(size_t)c*HW + p];
    op[p] = yp[p] + a*gm;
  }
}

extern "C" void kernel_launch(void* const* d_in, const int* in_sizes, int n_in,
                              void* d_out, int out_size, void* d_ws, size_t ws_size,
                              hipStream_t stream) {
  const float* x      = (const float*)d_in[0];
  const float* ln1_w  = (const float*)d_in[1];
  const float* ln1_b  = (const float*)d_in[2];
  const float* qkv_w  = (const float*)d_in[3];
  const float* qkv_b  = (const float*)d_in[4];
  const float* dw_w   = (const float*)d_in[5];
  const float* dw_b   = (const float*)d_in[6];
  const float* temp   = (const float*)d_in[7];
  const float* ca_w1  = (const float*)d_in[8];
  const float* ca_b1  = (const float*)d_in[9];
  const float* ca_w2  = (const float*)d_in[10];
  const float* ca_b2  = (const float*)d_in[11];
  const float* beta   = (const float*)d_in[12];
  const float* beta2  = (const float*)d_in[13];
  const float* ln2_w  = (const float*)d_in[14];
  const float* ln2_b  = (const float*)d_in[15];
  const float* conv4_w= (const float*)d_in[16];
  const float* conv4_b= (const float*)d_in[17];
  const float* conv5_w= (const float*)d_in[18];
  const float* conv5_b= (const float*)d_in[19];
  const float* gamma  = (const float*)d_in[20];

  float* ws   = (float*)d_ws;
  float* xn   = ws + OFF_XN;
  float* y1   = ws + OFF_Y1;
  float* bp   = ws + OFF_BP;
  float* se   = ws + OFF_SE;
  ushort* Qb  = (ushort*)(ws + OFF_QB);
  ushort* Kb  = (ushort*)(ws + OFF_KB);
  ushort* Vtb = (ushort*)(ws + OFF_VT);
  float* qkv1 = ws + OFF_QKV1;
  float* qkv2 = ws + OFF_QKV2;
  float* part = ws + OFF_PART;
  float* tn   = ws + OFF_TN;
  float* g    = ws + OFF_G;
  float* out  = (float*)d_out;

  k_ln1  <<<32,   256, 0, stream>>>(x, ln1_w, ln1_b, xn, bp);
  k_se   <<<1,    128, 0, stream>>>(bp, ca_w1, ca_b1, ca_w2, ca_b2, se);
  k_conv1<<<288,  256, 0, stream>>>(xn, qkv_w, qkv_b, qkv1);
  k_dw   <<<4608, 256, 0, stream>>>(qkv1, dw_w, dw_b, qkv2);
  k_prep <<<96,   256, 0, stream>>>(qkv2, temp, Qb, Kb, Vtb);
  k_attn <<<768,  256, 0, stream>>>(Qb, Kb, Vtb, part);
  k_comb <<<96,   256, 0, stream>>>(part, x, xn, se, beta, beta2, y1);
  k_ln2  <<<32,   256, 0, stream>>>(y1, ln2_w, ln2_b, tn);
  k_gate <<<384,  256, 0, stream>>>(tn, conv4_w, conv4_b, g);
  k_conv5<<<384,  256, 0, stream>>>(g, conv5_w, conv5_b, gamma, y1, out);
}

// Round 3
// 136.624 us; speedup vs baseline: 3.0124x; 1.3029x over previous
//
#include <hip/hip_runtime.h>
#include <cstddef>
#include <cmath>

#define BN 2
#define CH 48
#define HW 4096
#define NH 3
#define CPH 16
#define QC 144      // 3*CH
#define RR 3        // CH/16
#define KSPLIT 8
#define NPLANE 17   // 16 acc + 1 denom planes per (ks,bh)

typedef __attribute__((ext_vector_type(8))) short bf16x8;
typedef __attribute__((ext_vector_type(16))) float f32x16;
typedef __attribute__((ext_vector_type(4))) float f32x4;

// ---- workspace layout (floats) ----
constexpr size_t N_XN  = (size_t)BN*CH*HW;        // 393216
constexpr size_t N_QKV = (size_t)BN*QC*HW;        // 1179648
constexpr size_t N_BF  = (size_t)BN*NH*HW*16/2;   // 98304 f32 slots for bf16 [bh][n][16]
constexpr size_t N_PART = (size_t)KSPLIT*6*NPLANE*HW; // 3342336
constexpr size_t OFF_XN = 0;
constexpr size_t OFF_Y1 = OFF_XN + N_XN;
constexpr size_t OFF_BP = OFF_Y1 + N_XN;          // 32*CH
constexpr size_t OFF_SE = OFF_BP + 2048;
constexpr size_t OFF_QB = OFF_SE + 128;
constexpr size_t OFF_KB = OFF_QB + N_BF;
constexpr size_t OFF_VT = OFF_KB + N_BF;
constexpr size_t OFF_QKV1 = OFF_VT + N_BF;
constexpr size_t OFF_QKV2 = OFF_QKV1 + N_QKV;
constexpr size_t OFF_PART = OFF_QKV2 + N_QKV;
constexpr size_t OFF_TN   = OFF_PART + N_PART;
constexpr size_t OFF_G    = OFF_TN + N_XN;

#define LOG2E 1.4426950408889634f

static __device__ __forceinline__ unsigned pkbf(float a, float b) {
  unsigned ua = __float_as_uint(a), ub = __float_as_uint(b);
  ua = (ua + 0x7fffu + ((ua >> 16) & 1u)) >> 16;
  ub = (ub + 0x7fffu + ((ub >> 16) & 1u)) >> 16;
  return ua | (ub << 16);
}

static __device__ __forceinline__ unsigned cvtpk(float lo, float hi) {
  unsigned r;
  asm("v_cvt_pk_bf16_f32 %0, %1, %2" : "=v"(r) : "v"(lo), "v"(hi));
  return r;
}

// ---------- K1: LayerNorm over C (per pixel) + per-block pool partials ----------
__global__ __launch_bounds__(256) void k_ln1(const float* __restrict__ x,
                                             const float* __restrict__ lw,
                                             const float* __restrict__ lb,
                                             float* __restrict__ xn,
                                             float* __restrict__ bpool) {
  __shared__ float wsum[4][CH];
  int p = blockIdx.x*256 + threadIdx.x;
  int b = p >> 12, hw = p & 4095;
  const float* xp = x + (size_t)b*CH*HW + hw;
  float v[CH]; float s = 0.f, ss = 0.f;
#pragma unroll
  for (int c = 0; c < CH; ++c) { float t = xp[(size_t)c*HW]; v[c] = t; s += t; ss += t*t; }
  float mu = s * (1.f/CH);
  float var = ss * (1.f/CH) - mu*mu;
  float rs = rsqrtf(var + 1e-6f);
  float* xnp = xn + (size_t)b*CH*HW + hw;
  int lane = threadIdx.x & 63, wid = threadIdx.x >> 6;
#pragma unroll
  for (int c = 0; c < CH; ++c) {
    float t = lw[c] * ((v[c]-mu)*rs) + lb[c];
    v[c] = t;
    xnp[(size_t)c*HW] = t;
  }
#pragma unroll
  for (int c = 0; c < CH; ++c) {
    float r = v[c];
    r += __shfl_xor(r,32); r += __shfl_xor(r,16); r += __shfl_xor(r,8);
    r += __shfl_xor(r,4);  r += __shfl_xor(r,2);  r += __shfl_xor(r,1);
    if (lane == 0) wsum[wid][c] = r;
  }
  __syncthreads();
  if (threadIdx.x < CH) {
    float a = wsum[0][threadIdx.x] + wsum[1][threadIdx.x] + wsum[2][threadIdx.x] + wsum[3][threadIdx.x];
    bpool[(size_t)blockIdx.x*CH + threadIdx.x] = a;
  }
}

// ---------- K2: SE MLP ----------
__global__ void k_se(const float* __restrict__ bpool,
                     const float* __restrict__ w1, const float* __restrict__ b1,
                     const float* __restrict__ w2, const float* __restrict__ b2,
                     float* __restrict__ se) {
  __shared__ float pm[BN*CH];
  __shared__ float yr[BN*RR];
  int t = threadIdx.x;
  if (t < BN*CH) {
    int b = t / CH, c = t % CH;
    float a = 0.f;
    for (int i = 0; i < 16; ++i) a += bpool[(size_t)(b*16+i)*CH + c];
    pm[t] = a * (1.f/HW);
  }
  __syncthreads();
  if (t < BN*RR) {
    int b = t / RR, r = t % RR;
    float a = b1[r];
    for (int c = 0; c < CH; ++c) a += w1[r*CH+c] * pm[b*CH+c];
    yr[t] = fmaxf(a, 0.f);
  }
  __syncthreads();
  if (t < BN*CH) {
    int b = t / CH, c = t % CH;
    float a = b2[c];
    for (int r = 0; r < RR; ++r) a += w2[c*RR+r] * yr[b*RR+r];
    se[t] = 1.f / (1.f + __expf(-a));
  }
}

// ---------- K3: conv1x1 48 -> 144, 4 out-channels x 512-px strips ----------
__global__ __launch_bounds__(256) void k_conv1(const float* __restrict__ xn,
                                               const float* __restrict__ w,
                                               const float* __restrict__ bias,
                                               float* __restrict__ out) {
  int blk = blockIdx.x;               // b(2) x og(36) x strip(8)
  int strip = blk & 7;
  int og = (blk >> 3) % 36;
  int b = blk / 288;
  int o = og * 4;
  const float* xb = xn + (size_t)b*CH*HW;
  float b0 = bias[o], b1 = bias[o+1], b2 = bias[o+2], b3 = bias[o+3];
  for (int p = strip*512 + threadIdx.x; p < strip*512 + 512; p += 256) {
    float a0 = b0, a1 = b1, a2 = b2, a3 = b3;
#pragma unroll
    for (int c = 0; c < CH; ++c) {
      float xv = xb[(size_t)c*HW + p];
      a0 += w[(size_t)o*CH + c]     * xv;
      a1 += w[(size_t)(o+1)*CH + c] * xv;
      a2 += w[(size_t)(o+2)*CH + c] * xv;
      a3 += w[(size_t)(o+3)*CH + c] * xv;
    }
    out[((size_t)b*QC + o)*HW + p]     = a0;
    out[((size_t)b*QC + o + 1)*HW + p] = a1;
    out[((size_t)b*QC + o + 2)*HW + p] = a2;
    out[((size_t)b*QC + o + 3)*HW + p] = a3;
  }
}

// ---------- K4: depthwise 3x3 SAME ----------
__global__ __launch_bounds__(256) void k_dw(const float* __restrict__ in,
                                            const float* __restrict__ w,
                                            const float* __restrict__ bias,
                                            float* __restrict__ out) {
  int idx = blockIdx.x*256 + threadIdx.x;
  int p = idx & 4095;
  int ch = (idx >> 12) % QC;
  int b  = idx / (QC*HW);
  int y = p >> 6, xc = p & 63;
  const float* ip = in + ((size_t)b*QC + ch)*HW;
  const float* wc = w + (size_t)ch*9;
  float a = bias[ch];
#pragma unroll
  for (int dy = 0; dy < 3; ++dy) {
    int yy = y + dy - 1;
    if (yy < 0 || yy >= 64) continue;
#pragma unroll
    for (int dx = 0; dx < 3; ++dx) {
      int xx = xc + dx - 1;
      if (xx < 0 || xx >= 64) continue;
      a += wc[dy*3+dx] * ip[yy*64 + xx];
    }
  }
  out[idx] = a;
}

// ---------- K5: token transpose + l2norm(q,k) -> bf16; V transposed bf16 ----------
// log2e folded into q scale so attention can use exp2.
__global__ __launch_bounds__(256) void k_prep(const float* __restrict__ qkv,
                                              const float* __restrict__ temp,
                                              ushort* __restrict__ Qb,
                                              ushort* __restrict__ Kb,
                                              ushort* __restrict__ Vtb) {
  int t = blockIdx.x*256 + threadIdx.x;   // bh*HW + n
  int n = t & 4095; int bh = t >> 12;
  int b = bh / NH, h = bh % NH;
  const float* base = qkv + (size_t)b*QC*HW + n;
  float q[16], k[16], v[16];
  float sq = 0.f, sk = 0.f;
#pragma unroll
  for (int cc = 0; cc < 16; ++cc) {
    float qv = base[(size_t)(      h*16+cc)*HW];
    float kv = base[(size_t)( 48 + h*16+cc)*HW];
    float vv = base[(size_t)( 96 + h*16+cc)*HW];
    q[cc] = qv; k[cc] = kv; v[cc] = vv;
    sq += qv*qv; sk += kv*kv;
  }
  float tq = temp[h] * LOG2E / fmaxf(sqrtf(sq), 1e-12f);
  float ik = 1.f            / fmaxf(sqrtf(sk), 1e-12f);
  uint qp[8], kp[8];
#pragma unroll
  for (int i = 0; i < 8; ++i) {
    qp[i] = pkbf(q[2*i]*tq, q[2*i+1]*tq);
    kp[i] = pkbf(k[2*i]*ik, k[2*i+1]*ik);
  }
  uint4* qo = (uint4*)(Qb + (size_t)t*16);
  uint4* ko = (uint4*)(Kb + (size_t)t*16);
  qo[0] = make_uint4(qp[0],qp[1],qp[2],qp[3]);
  qo[1] = make_uint4(qp[4],qp[5],qp[6],qp[7]);
  ko[0] = make_uint4(kp[0],kp[1],kp[2],kp[3]);
  ko[1] = make_uint4(kp[4],kp[5],kp[6],kp[7]);
#pragma unroll
  for (int cc = 0; cc < 16; ++cc)
    Vtb[((size_t)bh*16 + cc)*HW + n] = (ushort)(pkbf(v[cc], 0.f) & 0xffffu);
}

// ---------- K6: MFMA flash attention partials ----------
// S^T = K.Q^T via mfma_32x32x16; exp(relu(s)) = max(exp2(s*log2e),1) (no running max
// needed since exp-args bounded by temp); P packed via v_cvt_pk_bf16_f32 into
// wave-private swizzled LDS; PV via mfma_16x16x32. Epilogue transposes partials
// through LDS to a PLANAR [plane][n] layout so the combine reads coalesced.
__global__ __launch_bounds__(256) void k_attn(const ushort* __restrict__ Qb,
                                              const ushort* __restrict__ Kb,
                                              const ushort* __restrict__ Vtb,
                                              float* __restrict__ part) {
  __shared__ ushort plds[4][32][32];   // [wave][q][key] bf16, 64B rows, swizzled 16B units
  __shared__ float eplds[4][32][NPLANE];
  int blk = blockIdx.x;                // bh(6) x qt(32) x ks(8)
  int ks = blk & (KSPLIT-1);
  int qt = (blk >> 3) & 31;
  int bh = blk >> 8;
  int lane = threadIdx.x & 63;
  int wid  = threadIdx.x >> 6;
  int l31 = lane & 31;
  int lhi = lane >> 5;                 // 0/1
  int qbase = qt*128 + wid*32;

  // persistent Q fragment (B-operand of swapped QK^T): Q[q=l31][ch=8*lhi..+7]
  bf16x8 qf = *(const bf16x8*)(Qb + ((size_t)bh*HW + qbase + l31)*16 + lhi*8);

  const f32x16 z16 = {0,0,0,0,0,0,0,0,0,0,0,0,0,0,0,0};
  f32x4 acc0 = {0,0,0,0}, acc1 = {0,0,0,0};
  float den = 0.f;
  char* prow = (char*)&plds[wid][0][0];
  int qr = lane & 15, gr = lane >> 4;
  int rdoff0 = qr*64 + 16*(gr ^ ((qr>>1)&3));

  int kbeg = ks * (HW/KSPLIT);
  for (int kk = kbeg; kk < kbeg + HW/KSPLIT; kk += 32) {
    // K fragment (A-operand): K[key=l31][ch=8*lhi..+7]
    bf16x8 kf = *(const bf16x8*)(Kb + ((size_t)bh*HW + kk + l31)*16 + lhi*8);
    f32x16 st = __builtin_amdgcn_mfma_f32_32x32x16_bf16(kf, qf, z16, 0, 0, 0);
    int sw = (l31 >> 1) & 3;
#pragma unroll
    for (int g4 = 0; g4 < 4; ++g4) {
      float e0 = fmaxf(exp2f(st[4*g4+0]), 1.f);
      float e1 = fmaxf(exp2f(st[4*g4+1]), 1.f);
      float e2 = fmaxf(exp2f(st[4*g4+2]), 1.f);
      float e3 = fmaxf(exp2f(st[4*g4+3]), 1.f);
      den += (e0+e1) + (e2+e3);
      uint2 pk;
      pk.x = cvtpk(e0, e1);
      pk.y = cvtpk(e2, e3);
      *(uint2*)(prow + l31*64 + 16*(g4 ^ sw) + 8*lhi) = pk;
    }
    // V fragment (B-operand of PV): Vt[ch=qr][key = kk + 8*gr .. +7]
    bf16x8 vf = *(const bf16x8*)(Vtb + ((size_t)bh*16 + qr)*HW + kk + 8*gr);
    bf16x8 pa0 = *(const bf16x8*)(prow + rdoff0);
    bf16x8 pa1 = *(const bf16x8*)(prow + 1024 + rdoff0);
    acc0 = __builtin_amdgcn_mfma_f32_16x16x32_bf16(pa0, vf, acc0, 0, 0, 0);
    acc1 = __builtin_amdgcn_mfma_f32_16x16x32_bf16(pa1, vf, acc1, 0, 0, 0);
  }

  // combine den over the two key-halves (lanes l and l^32 hold same q)
  den += __shfl_xor(den, 32);

  // stage accumulators into LDS: eplds[w][q_local][slot]
#pragma unroll
  for (int r = 0; r < 4; ++r) {
    eplds[wid][gr*4 + r][qr]      = acc0[r];
    eplds[wid][gr*4 + 16 + r][qr] = acc1[r];
  }
  if (lane < 32) eplds[wid][l31][16] = den;
  __syncthreads();

  // planar coalesced write-out: part[((ks*6+bh)*17 + slot)*HW + q_global]
  size_t pb = ((size_t)(ks*6 + bh))*NPLANE;
  for (int i = threadIdx.x; i < 4*32*NPLANE; i += 256) {
    int w = i / (32*NPLANE);
    int rem = i - w*(32*NPLANE);
    int cc = rem >> 5;
    int q = rem & 31;
    part[(pb + cc)*HW + qt*128 + w*32 + q] = eplds[w][q][cc];
  }
}

// ---------- K7: combine ksplits + y1 + LN2 fused (per pixel) ----------
__global__ __launch_bounds__(64) void k_comb2(const float* __restrict__ part,
                                              const float* __restrict__ x,
                                              const float* __restrict__ xn,
                                              const float* __restrict__ se,
                                              const float* __restrict__ beta,
                                              const float* __restrict__ beta2,
                                              const float* __restrict__ lw,
                                              const float* __restrict__ lb,
                                              float* __restrict__ y1,
                                              float* __restrict__ tn) {
  int p = blockIdx.x*64 + threadIdx.x;   // pixel: b*HW + n
  int b = p >> 12, n = p & 4095;
  float yv[CH];
#pragma unroll
  for (int h = 0; h < NH; ++h) {
    int bh = b*NH + h;
    float acc[16] = {0,0,0,0,0,0,0,0,0,0,0,0,0,0,0,0};
    float den = 0.f;
    for (int ks = 0; ks < KSPLIT; ++ks) {
      const float* pl = part + ((size_t)(ks*6 + bh))*NPLANE*HW + n;
#pragma unroll
      for (int cc = 0; cc < 16; ++cc) acc[cc] += pl[(size_t)cc*HW];
      den += pl[(size_t)16*HW];
    }
    float inv = 1.f / den;
#pragma unroll
    for (int cc = 0; cc < 16; ++cc) {
      int c = h*16 + cc;
      size_t idx = ((size_t)b*CH + c)*HW + n;
      yv[c] = x[idx] + xn[idx]*se[b*CH+c]*beta[c] + acc[cc]*inv*beta2[c];
    }
  }
  float s = 0.f, ss = 0.f;
#pragma unroll
  for (int c = 0; c < CH; ++c) { s += yv[c]; ss += yv[c]*yv[c]; }
  float mu = s * (1.f/CH);
  float rs = rsqrtf(ss*(1.f/CH) - mu*mu + 1e-6f);
  float* yp = y1 + (size_t)b*CH*HW + n;
  float* tp = tn + (size_t)b*CH*HW + n;
#pragma unroll
  for (int c = 0; c < CH; ++c) {
    yp[(size_t)c*HW] = yv[c];
    tp[(size_t)c*HW] = lw[c]*((yv[c]-mu)*rs) + lb[c];
  }
}

// ---------- K8b: conv4 + gate ----------
__global__ __launch_bounds__(256) void k_gate(const float* __restrict__ tn,
                                              const float* __restrict__ w4,
                                              const float* __restrict__ b4,
                                              float* __restrict__ g) {
  int blk = blockIdx.x;              // b(2) x o(48) x strip(8)
  int strip = blk & 7;
  int o = (blk >> 3) % CH;
  int b = blk / (CH*8);
  const float* w1 = w4 + (size_t)o*CH;
  const float* w2 = w4 + (size_t)(o+CH)*CH;
  const float* tb = tn + (size_t)b*CH*HW;
  float bb1 = b4[o], bb2 = b4[o+CH];
  float* gp = g + ((size_t)b*CH + o)*HW;
  for (int p = strip*512 + threadIdx.x; p < strip*512 + 512; p += 256) {
    float f1 = bb1, f2 = bb2;
#pragma unroll
    for (int c = 0; c < CH; ++c) {
      float xv = tb[(size_t)c*HW + p];
      f1 += w1[c]*xv; f2 += w2[c]*xv;
    }
    gp[p] = f1*f2;
  }
}

// ---------- K8c: conv5 + residual ----------
__global__ __launch_bounds__(256) void k_conv5(const float* __restrict__ g,
                                               const float* __restrict__ w5,
                                               const float* __restrict__ b5,
                                               const float* __restrict__ gamma,
                                               const float* __restrict__ y1,
                                               float* __restrict__ out) {
  int blk = blockIdx.x;              // b(2) x o(48) x strip(8)
  int strip = blk & 7;
  int o = (blk >> 3) % CH;
  int b = blk / (CH*8);
  const float* wrow = w5 + (size_t)o*CH;
  const float* gb = g + (size_t)b*CH*HW;
  float bo = b5[o], gm = gamma[o];
  const float* yp = y1 + ((size_t)b*CH + o)*HW;
  float* op = out + ((size_t)b*CH + o)*HW;
  for (int p = strip*512 + threadIdx.x; p < strip*512 + 512; p += 256) {
    float a = bo;
#pragma unroll
    for (int c = 0; c < CH; ++c) a += wrow[c] * gb[(size_t)c*HW + p];
    op[p] = yp[p] + a*gm;
  }
}

extern "C" void kernel_launch(void* const* d_in, const int* in_sizes, int n_in,
                              void* d_out, int out_size, void* d_ws, size_t ws_size,
                              hipStream_t stream) {
  const float* x      = (const float*)d_in[0];
  const float* ln1_w  = (const float*)d_in[1];
  const float* ln1_b  = (const float*)d_in[2];
  const float* qkv_w  = (const float*)d_in[3];
  const float* qkv_b  = (const float*)d_in[4];
  const float* dw_w   = (const float*)d_in[5];
  const float* dw_b   = (const float*)d_in[6];
  const float* temp   = (const float*)d_in[7];
  const float* ca_w1  = (const float*)d_in[8];
  const float* ca_b1  = (const float*)d_in[9];
  const float* ca_w2  = (const float*)d_in[10];
  const float* ca_b2  = (const float*)d_in[11];
  const float* beta   = (const float*)d_in[12];
  const float* beta2  = (const float*)d_in[13];
  const float* ln2_w  = (const float*)d_in[14];
  const float* ln2_b  = (const float*)d_in[15];
  const float* conv4_w= (const float*)d_in[16];
  const float* conv4_b= (const float*)d_in[17];
  const float* conv5_w= (const float*)d_in[18];
  const float* conv5_b= (const float*)d_in[19];
  const float* gamma  = (const float*)d_in[20];

  float* ws   = (float*)d_ws;
  float* xn   = ws + OFF_XN;
  float* y1   = ws + OFF_Y1;
  float* bp   = ws + OFF_BP;
  float* se   = ws + OFF_SE;
  ushort* Qb  = (ushort*)(ws + OFF_QB);
  ushort* Kb  = (ushort*)(ws + OFF_KB);
  ushort* Vtb = (ushort*)(ws + OFF_VT);
  float* qkv1 = ws + OFF_QKV1;
  float* qkv2 = ws + OFF_QKV2;
  float* part = ws + OFF_PART;
  float* tn   = ws + OFF_TN;
  float* g    = ws + OFF_G;
  float* out  = (float*)d_out;

  k_ln1  <<<32,   256, 0, stream>>>(x, ln1_w, ln1_b, xn, bp);
  k_se   <<<1,    128, 0, stream>>>(bp, ca_w1, ca_b1, ca_w2, ca_b2, se);
  k_conv1<<<576,  256, 0, stream>>>(xn, qkv_w, qkv_b, qkv1);
  k_dw   <<<4608, 256, 0, stream>>>(qkv1, dw_w, dw_b, qkv2);
  k_prep <<<96,   256, 0, stream>>>(qkv2, temp, Qb, Kb, Vtb);
  k_attn <<<1536, 256, 0, stream>>>(Qb, Kb, Vtb, part);
  k_comb2<<<128,  64,  0, stream>>>(part, x, xn, se, beta, beta2, ln2_w, ln2_b, y1, tn);
  k_gate <<<768,  256, 0, stream>>>(tn, conv4_w, conv4_b, g);
  k_conv5<<<768,  256, 0, stream>>>(g, conv5_w, conv5_b, gamma, y1, out);
}

// Round 4
// 128.672 us; speedup vs baseline: 3.1986x; 1.0618x over previous
//
#include <hip/hip_runtime.h>
#include <cstddef>
#include <cmath>

#define BN 2
#define CH 48
#define HW 4096
#define NH 3
#define QC 144      // 3*CH
#define RR 3        // CH/16
#define KSPLIT 8
#define NPLANE 17   // 16 acc + 1 denom planes per (ks,bh)
#define LOG2E 1.4426950408889634f

typedef __attribute__((ext_vector_type(8))) short bf16x8;
typedef __attribute__((ext_vector_type(16))) float f32x16;
typedef __attribute__((ext_vector_type(4))) float f32x4;

// ---- workspace layout (floats) ----
constexpr size_t OFF_BP  = 0;                      // 128*48
constexpr size_t OFF_SE  = 6144;                   // 96->128
constexpr size_t OFF_QB  = 6272;                   // 98304 (bf16 [bh][n][16])
constexpr size_t OFF_KB  = OFF_QB + 98304;
constexpr size_t OFF_VT  = OFF_KB + 98304;
constexpr size_t OFF_Y1  = OFF_VT + 98304;         // 393216
constexpr size_t OFF_TN  = OFF_Y1 + 393216;
constexpr size_t OFF_G   = OFF_TN + 393216;
constexpr size_t OFF_QKV1= OFF_G  + 393216;        // 1179648
constexpr size_t OFF_QKV2= OFF_QKV1 + 1179648;     // 1179648
constexpr size_t OFF_PART= OFF_QKV1;               // aliases qkv1+qkv2 (dead after k_prep); 3342336
constexpr size_t OFF_RED = OFF_PART + (size_t)KSPLIT*6*NPLANE*HW;  // 417792

static __device__ __forceinline__ unsigned cvtpk(float lo, float hi) {
  unsigned r;
  asm("v_cvt_pk_bf16_f32 %0, %1, %2" : "=v"(r) : "v"(lo), "v"(hi));
  return r;
}

static __device__ __forceinline__ float fexp2(float x) {
#if __has_builtin(__builtin_amdgcn_exp2f)
  return __builtin_amdgcn_exp2f(x);
#else
  float r; asm("v_exp_f32 %0, %1" : "=v"(r) : "v"(x)); return r;
#endif
}

// ---------- K_A: fused LN1 + pool-partial + conv1x1(48->144) ----------
// block = 64-pixel tile, 256 thr. Phase1: 4-way channel-split LN into LDS tile.
// Phase2: wave w computes output channels w*36..+36 for all 64 px (weights via
// wave-uniform scalar loads). xn is never materialized to HBM.
__global__ __launch_bounds__(256) void k_lnconv(const float* __restrict__ x,
                                                const float* __restrict__ lw,
                                                const float* __restrict__ lb,
                                                const float* __restrict__ w,
                                                const float* __restrict__ bias,
                                                float* __restrict__ qkv1,
                                                float* __restrict__ bpool) {
  __shared__ float xt[CH][65];
  __shared__ float sums[4][64], sqs[4][64];
  int blk = blockIdx.x;          // b*64 + tile
  int b = blk >> 6, tile = blk & 63;
  int t = threadIdx.x;
  int px = t & 63, cq = t >> 6;
  int n0 = tile*64;
  const float* xb = x + ((size_t)b*CH)*HW + n0 + px;
  float v[12]; float s = 0.f, ss = 0.f;
#pragma unroll
  for (int j = 0; j < 12; ++j) {
    float vv = xb[(size_t)(cq*12 + j)*HW];
    v[j] = vv; s += vv; ss += vv*vv;
  }
  sums[cq][px] = s; sqs[cq][px] = ss;
  __syncthreads();
  float stot = sums[0][px]+sums[1][px]+sums[2][px]+sums[3][px];
  float sstot = sqs[0][px]+sqs[1][px]+sqs[2][px]+sqs[3][px];
  float mu = stot * (1.f/CH);
  float rs = rsqrtf(sstot*(1.f/CH) - mu*mu + 1e-6f);
#pragma unroll
  for (int j = 0; j < 12; ++j) {
    int c = cq*12 + j;
    xt[c][px] = lw[c]*((v[j]-mu)*rs) + lb[c];
  }
  __syncthreads();
  if (t < CH) {
    float a = 0.f;
#pragma unroll
    for (int p2 = 0; p2 < 64; ++p2) a += xt[t][p2];
    bpool[(size_t)blk*CH + t] = a;
  }
  float xv[CH];
#pragma unroll
  for (int c = 0; c < CH; ++c) xv[c] = xt[c][px];
  float* op = qkv1 + (size_t)b*QC*HW + n0 + px;
#pragma unroll 4
  for (int oi = 0; oi < 36; ++oi) {
    int o = cq*36 + oi;
    float a = bias[o];
#pragma unroll
    for (int c = 0; c < CH; ++c) a += w[(size_t)o*CH + c]*xv[c];
    op[(size_t)o*HW] = a;
  }
}

// ---------- K2: SE MLP ----------
__global__ void k_se(const float* __restrict__ bpool,
                     const float* __restrict__ w1, const float* __restrict__ b1,
                     const float* __restrict__ w2, const float* __restrict__ b2,
                     float* __restrict__ se) {
  __shared__ float pm[BN*CH];
  __shared__ float yr[BN*RR];
  int t = threadIdx.x;
  if (t < BN*CH) {
    int b = t / CH, c = t % CH;
    float a = 0.f;
    for (int i = 0; i < 64; ++i) a += bpool[(size_t)(b*64+i)*CH + c];
    pm[t] = a * (1.f/HW);
  }
  __syncthreads();
  if (t < BN*RR) {
    int b = t / RR, r = t % RR;
    float a = b1[r];
    for (int c = 0; c < CH; ++c) a += w1[r*CH+c] * pm[b*CH+c];
    yr[t] = fmaxf(a, 0.f);
  }
  __syncthreads();
  if (t < BN*CH) {
    int b = t / CH, c = t % CH;
    float a = b2[c];
    for (int r = 0; r < RR; ++r) a += w2[c*RR+r] * yr[b*RR+r];
    se[t] = 1.f / (1.f + __expf(-a));
  }
}

// ---------- K4: depthwise 3x3 SAME ----------
__global__ __launch_bounds__(256) void k_dw(const float* __restrict__ in,
                                            const float* __restrict__ w,
                                            const float* __restrict__ bias,
                                            float* __restrict__ out) {
  int idx = blockIdx.x*256 + threadIdx.x;
  int p = idx & 4095;
  int ch = (idx >> 12) % QC;
  int b  = idx / (QC*HW);
  int y = p >> 6, xc = p & 63;
  const float* ip = in + ((size_t)b*QC + ch)*HW;
  const float* wc = w + (size_t)ch*9;
  float a = bias[ch];
#pragma unroll
  for (int dy = 0; dy < 3; ++dy) {
    int yy = y + dy - 1;
    if (yy < 0 || yy >= 64) continue;
#pragma unroll
    for (int dx = 0; dx < 3; ++dx) {
      int xx = xc + dx - 1;
      if (xx < 0 || xx >= 64) continue;
      a += wc[dy*3+dx] * ip[yy*64 + xx];
    }
  }
  out[idx] = a;
}

// ---------- K5: token transpose + l2norm(q,k) -> bf16; V transposed bf16 ----------
__global__ __launch_bounds__(128) void k_prep(const float* __restrict__ qkv,
                                              const float* __restrict__ temp,
                                              ushort* __restrict__ Qb,
                                              ushort* __restrict__ Kb,
                                              ushort* __restrict__ Vtb) {
  int t = blockIdx.x*128 + threadIdx.x;   // bh*HW + n
  int n = t & 4095; int bh = t >> 12;
  int b = bh / NH, h = bh % NH;
  const float* base = qkv + (size_t)b*QC*HW + n;
  float q[16], k[16], v[16];
  float sq = 0.f, sk = 0.f;
#pragma unroll
  for (int cc = 0; cc < 16; ++cc) {
    float qv = base[(size_t)(      h*16+cc)*HW];
    float kv = base[(size_t)( 48 + h*16+cc)*HW];
    float vv = base[(size_t)( 96 + h*16+cc)*HW];
    q[cc] = qv; k[cc] = kv; v[cc] = vv;
    sq += qv*qv; sk += kv*kv;
  }
  float tq = temp[h] * LOG2E / fmaxf(sqrtf(sq), 1e-12f);
  float ik = 1.f            / fmaxf(sqrtf(sk), 1e-12f);
  uint qp[8], kp[8];
#pragma unroll
  for (int i = 0; i < 8; ++i) {
    qp[i] = cvtpk(q[2*i]*tq, q[2*i+1]*tq);
    kp[i] = cvtpk(k[2*i]*ik, k[2*i+1]*ik);
  }
  uint4* qo = (uint4*)(Qb + (size_t)t*16);
  uint4* ko = (uint4*)(Kb + (size_t)t*16);
  qo[0] = make_uint4(qp[0],qp[1],qp[2],qp[3]);
  qo[1] = make_uint4(qp[4],qp[5],qp[6],qp[7]);
  ko[0] = make_uint4(kp[0],kp[1],kp[2],kp[3]);
  ko[1] = make_uint4(kp[4],kp[5],kp[6],kp[7]);
#pragma unroll
  for (int cc = 0; cc < 16; ++cc)
    Vtb[((size_t)bh*16 + cc)*HW + n] = (ushort)(cvtpk(v[cc], v[cc]) & 0xffffu);
}

// ---------- K6: MFMA flash attention, software-pipelined ----------
// S^T = K.Q^T (mfma_32x32x16); e = max(v_exp(s),1) — exact relu-softmax since
// args bounded; pack via v_cvt_pk_bf16_f32 into double-buffered wave-private
// swizzled LDS; PV + denominator both via mfma_16x16x32 (den = P @ ones).
// S_{i+1} computed between pack(i) and PV(i) to cover the LDS turnaround.
__global__ __launch_bounds__(256) void k_attn(const ushort* __restrict__ Qb,
                                              const ushort* __restrict__ Kb,
                                              const ushort* __restrict__ Vtb,
                                              float* __restrict__ part) {
  __shared__ ushort plds[4][2][32][32];   // [wave][dbuf][q][key]
  __shared__ float eplds[4][32][NPLANE];
  int blk = blockIdx.x;                // bh(6) x qt(32) x ks(8)
  int ks = blk & (KSPLIT-1);
  int qt = (blk >> 3) & 31;
  int bh = blk >> 8;
  int lane = threadIdx.x & 63;
  int wid  = threadIdx.x >> 6;
  int l31 = lane & 31;
  int lhi = lane >> 5;
  int qbase = qt*128 + wid*32;

  bf16x8 qf = *(const bf16x8*)(Qb + ((size_t)bh*HW + qbase + l31)*16 + lhi*8);

  const f32x16 z16 = {0,0,0,0,0,0,0,0,0,0,0,0,0,0,0,0};
  const short oneb = (short)0x3f80;
  const bf16x8 ones = {oneb,oneb,oneb,oneb,oneb,oneb,oneb,oneb};
  f32x4 acc0 = {0,0,0,0}, acc1 = {0,0,0,0};
  f32x4 accD0 = {0,0,0,0}, accD1 = {0,0,0,0};
  char* base = (char*)&plds[wid][0][0][0];
  int qr = lane & 15, gr = lane >> 4;
  int rdoff0 = qr*64 + 16*(gr ^ ((qr>>1)&3));
  int sw = (l31 >> 1) & 3;
  int wroff = l31*64 + 8*lhi;

  const ushort* Kbase = Kb + (size_t)bh*HW*16;
  const ushort* Vbase = Vtb + ((size_t)bh*16 + qr)*HW;
  int kbeg = ks * (HW/KSPLIT);
  constexpr int ITERS = (HW/KSPLIT)/32;   // 16

  bf16x8 kf = *(const bf16x8*)(Kbase + (size_t)(kbeg + l31)*16 + lhi*8);
  f32x16 st = __builtin_amdgcn_mfma_f32_32x32x16_bf16(kf, qf, z16, 0, 0, 0);

#pragma unroll 2
  for (int i = 0; i < ITERS; ++i) {
    int kk = kbeg + i*32;
    char* wb = base + (i & 1)*2048;
    // pack exp(relu(S_i)) -> LDS
#pragma unroll
    for (int g4 = 0; g4 < 4; ++g4) {
      float e0 = fmaxf(fexp2(st[4*g4+0]), 1.f);
      float e1 = fmaxf(fexp2(st[4*g4+1]), 1.f);
      float e2 = fmaxf(fexp2(st[4*g4+2]), 1.f);
      float e3 = fmaxf(fexp2(st[4*g4+3]), 1.f);
      uint2 pk;
      pk.x = cvtpk(e0, e1);
      pk.y = cvtpk(e2, e3);
      *(uint2*)(wb + wroff + 16*(g4 ^ sw)) = pk;
    }
    // S_{i+1} overlaps the LDS turnaround
    if (i + 1 < ITERS) {
      kf = *(const bf16x8*)(Kbase + (size_t)(kk + 32 + l31)*16 + lhi*8);
      st = __builtin_amdgcn_mfma_f32_32x32x16_bf16(kf, qf, z16, 0, 0, 0);
    }
    // PV_i + den_i
    bf16x8 vf = *(const bf16x8*)(Vbase + kk + 8*gr);
    bf16x8 pa0 = *(const bf16x8*)(wb + rdoff0);
    bf16x8 pa1 = *(const bf16x8*)(wb + 1024 + rdoff0);
    acc0  = __builtin_amdgcn_mfma_f32_16x16x32_bf16(pa0, vf, acc0, 0, 0, 0);
    acc1  = __builtin_amdgcn_mfma_f32_16x16x32_bf16(pa1, vf, acc1, 0, 0, 0);
    accD0 = __builtin_amdgcn_mfma_f32_16x16x32_bf16(pa0, ones, accD0, 0, 0, 0);
    accD1 = __builtin_amdgcn_mfma_f32_16x16x32_bf16(pa1, ones, accD1, 0, 0, 0);
  }

  // stage accumulators: eplds[w][q_local][slot]
#pragma unroll
  for (int r = 0; r < 4; ++r) {
    eplds[wid][gr*4 + r][qr]      = acc0[r];
    eplds[wid][gr*4 + 16 + r][qr] = acc1[r];
  }
  if (qr == 0) {
#pragma unroll
    for (int r = 0; r < 4; ++r) {
      eplds[wid][gr*4 + r][16]      = accD0[r];
      eplds[wid][gr*4 + 16 + r][16] = accD1[r];
    }
  }
  __syncthreads();
  size_t pb = ((size_t)(ks*6 + bh))*NPLANE;
  for (int i = threadIdx.x; i < 4*32*NPLANE; i += 256) {
    int w = i / (32*NPLANE);
    int rem = i - w*(32*NPLANE);
    int cc = rem >> 5;
    int q = rem & 31;
    part[(pb + cc)*HW + qt*128 + w*32 + q] = eplds[w][q][cc];
  }
}

// ---------- K_red: sum over ksplits (fully parallel) ----------
__global__ __launch_bounds__(256) void k_red(const float* __restrict__ part,
                                             float* __restrict__ red) {
  int idx = blockIdx.x*256 + threadIdx.x;   // (bh*17+slot)*HW + n, 102*4096
  int n = idx & 4095;
  int sl = idx >> 12;
  int bh = sl / NPLANE, cc = sl - bh*NPLANE;
  float a = 0.f;
#pragma unroll
  for (int ks = 0; ks < KSPLIT; ++ks)
    a += part[(size_t)((ks*6+bh)*NPLANE + cc)*HW + n];
  red[(size_t)sl*HW + n] = a;
}

// ---------- K7: per-pixel: LN1 recompute + SE + attn combine + LN2 ----------
__global__ __launch_bounds__(64) void k_comb3(const float* __restrict__ red,
                                              const float* __restrict__ x,
                                              const float* __restrict__ lw1,
                                              const float* __restrict__ lb1,
                                              const float* __restrict__ se,
                                              const float* __restrict__ beta,
                                              const float* __restrict__ beta2,
                                              const float* __restrict__ lw2,
                                              const float* __restrict__ lb2,
                                              float* __restrict__ y1,
                                              float* __restrict__ tn) {
  int p = blockIdx.x*64 + threadIdx.x;
  int b = p >> 12, n = p & 4095;
  const float* xp = x + (size_t)b*CH*HW + n;
  float xv[CH]; float s = 0.f, ss = 0.f;
#pragma unroll
  for (int c = 0; c < CH; ++c) { float t = xp[(size_t)c*HW]; xv[c] = t; s += t; ss += t*t; }
  float mu = s*(1.f/CH), rs = rsqrtf(ss*(1.f/CH)-mu*mu+1e-6f);
  float yv[CH];
#pragma unroll
  for (int h = 0; h < NH; ++h) {
    const float* rp = red + (size_t)((b*NH+h)*NPLANE)*HW + n;
    float inv = 1.f / rp[(size_t)16*HW];
#pragma unroll
    for (int cc = 0; cc < 16; ++cc) {
      int c = h*16+cc;
      float xnv = lw1[c]*((xv[c]-mu)*rs)+lb1[c];
      yv[c] = xv[c] + xnv*se[b*CH+c]*beta[c] + rp[(size_t)cc*HW]*inv*beta2[c];
    }
  }
  float s2 = 0.f, ss2 = 0.f;
#pragma unroll
  for (int c = 0; c < CH; ++c) { s2 += yv[c]; ss2 += yv[c]*yv[c]; }
  float mu2 = s2*(1.f/CH), rs2 = rsqrtf(ss2*(1.f/CH)-mu2*mu2+1e-6f);
  float* yp = y1 + (size_t)b*CH*HW + n;
  float* tp = tn + (size_t)b*CH*HW + n;
#pragma unroll
  for (int c = 0; c < CH; ++c) {
    yp[(size_t)c*HW] = yv[c];
    tp[(size_t)c*HW] = lw2[c]*((yv[c]-mu2)*rs2)+lb2[c];
  }
}

// ---------- K8b: conv4 + gate ----------
__global__ __launch_bounds__(256) void k_gate(const float* __restrict__ tn,
                                              const float* __restrict__ w4,
                                              const float* __restrict__ b4,
                                              float* __restrict__ g) {
  int blk = blockIdx.x;              // b(2) x o(48) x strip(8)
  int strip = blk & 7;
  int o = (blk >> 3) % CH;
  int b = blk / (CH*8);
  const float* w1 = w4 + (size_t)o*CH;
  const float* w2 = w4 + (size_t)(o+CH)*CH;
  const float* tb = tn + (size_t)b*CH*HW;
  float bb1 = b4[o], bb2 = b4[o+CH];
  float* gp = g + ((size_t)b*CH + o)*HW;
  for (int p = strip*512 + threadIdx.x; p < strip*512 + 512; p += 256) {
    float f1 = bb1, f2 = bb2;
#pragma unroll
    for (int c = 0; c < CH; ++c) {
      float xv = tb[(size_t)c*HW + p];
      f1 += w1[c]*xv; f2 += w2[c]*xv;
    }
    gp[p] = f1*f2;
  }
}

// ---------- K8c: conv5 + residual ----------
__global__ __launch_bounds__(256) void k_conv5(const float* __restrict__ g,
                                               const float* __restrict__ w5,
                                               const float* __restrict__ b5,
                                               const float* __restrict__ gamma,
                                               const float* __restrict__ y1,
                                               float* __restrict__ out) {
  int blk = blockIdx.x;              // b(2) x o(48) x strip(8)
  int strip = blk & 7;
  int o = (blk >> 3) % CH;
  int b = blk / (CH*8);
  const float* wrow = w5 + (size_t)o*CH;
  const float* gb = g + (size_t)b*CH*HW;
  float bo = b5[o], gm = gamma[o];
  const float* yp = y1 + ((size_t)b*CH + o)*HW;
  float* op = out + ((size_t)b*CH + o)*HW;
  for (int p = strip*512 + threadIdx.x; p < strip*512 + 512; p += 256) {
    float a = bo;
#pragma unroll
    for (int c = 0; c < CH; ++c) a += wrow[c] * gb[(size_t)c*HW + p];
    op[p] = yp[p] + a*gm;
  }
}

extern "C" void kernel_launch(void* const* d_in, const int* in_sizes, int n_in,
                              void* d_out, int out_size, void* d_ws, size_t ws_size,
                              hipStream_t stream) {
  const float* x      = (const float*)d_in[0];
  const float* ln1_w  = (const float*)d_in[1];
  const float* ln1_b  = (const float*)d_in[2];
  const float* qkv_w  = (const float*)d_in[3];
  const float* qkv_b  = (const float*)d_in[4];
  const float* dw_w   = (const float*)d_in[5];
  const float* dw_b   = (const float*)d_in[6];
  const float* temp   = (const float*)d_in[7];
  const float* ca_w1  = (const float*)d_in[8];
  const float* ca_b1  = (const float*)d_in[9];
  const float* ca_w2  = (const float*)d_in[10];
  const float* ca_b2  = (const float*)d_in[11];
  const float* beta   = (const float*)d_in[12];
  const float* beta2  = (const float*)d_in[13];
  const float* ln2_w  = (const float*)d_in[14];
  const float* ln2_b  = (const float*)d_in[15];
  const float* conv4_w= (const float*)d_in[16];
  const float* conv4_b= (const float*)d_in[17];
  const float* conv5_w= (const float*)d_in[18];
  const float* conv5_b= (const float*)d_in[19];
  const float* gamma  = (const float*)d_in[20];

  float* ws   = (float*)d_ws;
  float* bp   = ws + OFF_BP;
  float* se   = ws + OFF_SE;
  ushort* Qb  = (ushort*)(ws + OFF_QB);
  ushort* Kb  = (ushort*)(ws + OFF_KB);
  ushort* Vtb = (ushort*)(ws + OFF_VT);
  float* y1   = ws + OFF_Y1;
  float* tn   = ws + OFF_TN;
  float* g    = ws + OFF_G;
  float* qkv1 = ws + OFF_QKV1;
  float* qkv2 = ws + OFF_QKV2;
  float* part = ws + OFF_PART;
  float* red  = ws + OFF_RED;
  float* out  = (float*)d_out;

  k_lnconv<<<128, 256, 0, stream>>>(x, ln1_w, ln1_b, qkv_w, qkv_b, qkv1, bp);
  k_se    <<<1,   128, 0, stream>>>(bp, ca_w1, ca_b1, ca_w2, ca_b2, se);
  k_dw    <<<4608,256, 0, stream>>>(qkv1, dw_w, dw_b, qkv2);
  k_prep  <<<192, 128, 0, stream>>>(qkv2, temp, Qb, Kb, Vtb);
  k_attn  <<<1536,256, 0, stream>>>(Qb, Kb, Vtb, part);
  k_red   <<<1632,256, 0, stream>>>(part, red);
  k_comb3 <<<128, 64,  0, stream>>>(red, x, ln1_w, ln1_b, se, beta, beta2,
                                    ln2_w, ln2_b, y1, tn);
  k_gate  <<<768, 256, 0, stream>>>(tn, conv4_w, conv4_b, g);
  k_conv5 <<<768, 256, 0, stream>>>(g, conv5_w, conv5_b, gamma, y1, out);
}

// Round 5
// 119.625 us; speedup vs baseline: 3.4405x; 1.0756x over previous
//
#include <hip/hip_runtime.h>
#include <cstddef>
#include <cmath>

#define BN 2
#define CH 48
#define HW 4096
#define NH 3
#define QC 144      // 3*CH
#define RR 3        // CH/16
#define KSPLIT 8
#define NPLANE 17   // 16 acc + 1 denom planes per (ks,bh)
#define LOG2E 1.4426950408889634f

typedef __attribute__((ext_vector_type(8))) short bf16x8;
typedef __attribute__((ext_vector_type(16))) float f32x16;
typedef __attribute__((ext_vector_type(4))) float f32x4;

// ---- workspace layout (floats) ----
constexpr size_t OFF_BP  = 0;                       // 256*48 = 12288
constexpr size_t OFF_SE  = 12288;                   // 96 -> 128
constexpr size_t OFF_QB  = 12416;                   // 98304 (bf16 [bh][n][16])
constexpr size_t OFF_KB  = OFF_QB + 98304;
constexpr size_t OFF_VT  = OFF_KB + 98304;
constexpr size_t OFF_Y1  = OFF_VT + 98304;          // 393216
constexpr size_t OFF_TN  = OFF_Y1 + 393216;
constexpr size_t OFF_G   = OFF_TN + 393216;
constexpr size_t OFF_QKV1= OFF_G  + 393216;         // 1179648
constexpr size_t OFF_PART= OFF_QKV1 + 1179648;      // 3342336

static __device__ __forceinline__ unsigned cvtpk(float lo, float hi) {
  unsigned r;
  asm("v_cvt_pk_bf16_f32 %0, %1, %2" : "=v"(r) : "v"(lo), "v"(hi));
  return r;
}

static __device__ __forceinline__ float fexp2(float x) {
#if __has_builtin(__builtin_amdgcn_exp2f)
  return __builtin_amdgcn_exp2f(x);
#else
  float r; asm("v_exp_f32 %0, %1" : "=v"(r) : "v"(x)); return r;
#endif
}

// ---------- K_A: fused LN1 + pool-partial + conv1x1(48->144) ----------
// 32-px tiles, 256 thr (8-way channel split for LN; 8x18 output split for conv).
__global__ __launch_bounds__(256) void k_lnconv(const float* __restrict__ x,
                                                const float* __restrict__ lw,
                                                const float* __restrict__ lb,
                                                const float* __restrict__ w,
                                                const float* __restrict__ bias,
                                                float* __restrict__ qkv1,
                                                float* __restrict__ bpool) {
  __shared__ float xt[CH][33];
  __shared__ float sums[8][32], sqs[8][32];
  int blk = blockIdx.x;          // b*128 + tile
  int b = blk >> 7, tile = blk & 127;
  int t = threadIdx.x;
  int px = t & 31, cq = t >> 5;  // 8 channel groups of 6
  int n0 = tile*32;
  const float* xb = x + (size_t)b*CH*HW + n0 + px;
  float v[6]; float s = 0.f, ss = 0.f;
#pragma unroll
  for (int j = 0; j < 6; ++j) {
    float vv = xb[(size_t)(cq*6 + j)*HW];
    v[j] = vv; s += vv; ss += vv*vv;
  }
  sums[cq][px] = s; sqs[cq][px] = ss;
  __syncthreads();
  float stot = 0.f, sstot = 0.f;
#pragma unroll
  for (int i = 0; i < 8; ++i) { stot += sums[i][px]; sstot += sqs[i][px]; }
  float mu = stot * (1.f/CH);
  float rs = rsqrtf(sstot*(1.f/CH) - mu*mu + 1e-6f);
#pragma unroll
  for (int j = 0; j < 6; ++j) {
    int c = cq*6 + j;
    xt[c][px] = lw[c]*((v[j]-mu)*rs) + lb[c];
  }
  __syncthreads();
  if (t < CH) {
    float a = 0.f;
#pragma unroll
    for (int p2 = 0; p2 < 32; ++p2) a += xt[t][p2];
    bpool[(size_t)blk*CH + t] = a;
  }
  float xv[CH];
#pragma unroll
  for (int c = 0; c < CH; ++c) xv[c] = xt[c][px];
  float* op = qkv1 + (size_t)b*QC*HW + n0 + px;
#pragma unroll 3
  for (int oi = 0; oi < 18; ++oi) {
    int o = cq*18 + oi;
    float a = bias[o];
#pragma unroll
    for (int c = 0; c < CH; ++c) a += w[(size_t)o*CH + c]*xv[c];
    op[(size_t)o*HW] = a;
  }
}

// ---------- K2: SE MLP ----------
__global__ void k_se(const float* __restrict__ bpool,
                     const float* __restrict__ w1, const float* __restrict__ b1,
                     const float* __restrict__ w2, const float* __restrict__ b2,
                     float* __restrict__ se) {
  __shared__ float pm[BN*CH];
  __shared__ float yr[BN*RR];
  int t = threadIdx.x;
  if (t < BN*CH) {
    int b = t / CH, c = t % CH;
    float a = 0.f;
    for (int i = 0; i < 128; ++i) a += bpool[(size_t)(b*128+i)*CH + c];
    pm[t] = a * (1.f/HW);
  }
  __syncthreads();
  if (t < BN*RR) {
    int b = t / RR, r = t % RR;
    float a = b1[r];
    for (int c = 0; c < CH; ++c) a += w1[r*CH+c] * pm[b*CH+c];
    yr[t] = fmaxf(a, 0.f);
  }
  __syncthreads();
  if (t < BN*CH) {
    int b = t / CH, c = t % CH;
    float a = b2[c];
    for (int r = 0; r < RR; ++r) a += w2[c*RR+r] * yr[b*RR+r];
    se[t] = 1.f / (1.f + __expf(-a));
  }
}

// ---------- K3: fused depthwise3x3 + token norm/pack ----------
// block = (bh, image row); 128 thr: wave w handles cc = w*8..w*8+7 for all 64 px.
__global__ __launch_bounds__(128) void k_dwprep(const float* __restrict__ qkv1,
                                                const float* __restrict__ dww,
                                                const float* __restrict__ dwb,
                                                const float* __restrict__ temp,
                                                ushort* __restrict__ Qb,
                                                ushort* __restrict__ Kb,
                                                ushort* __restrict__ Vtb) {
  __shared__ float sqq[2][64], sqk[2][64];
  int blk = blockIdx.x;               // bh*64 + row
  int row = blk & 63, bh = blk >> 6;
  int b = bh / NH, h = bh % NH;
  int lane = threadIdx.x & 63, wv = threadIdx.x >> 6;
  int n = row*64 + lane;
  const float* base = qkv1 + (size_t)b*QC*HW;

  float q[8], k[8], v[8];
  float sq = 0.f, sk = 0.f;
#pragma unroll 2
  for (int j = 0; j < 8; ++j) {
    int cc = wv*8 + j;
#pragma unroll
    for (int which = 0; which < 3; ++which) {
      int c = which*48 + h*16 + cc;
      const float* ip = base + (size_t)c*HW;
      const float* wc = dww + (size_t)c*9;
      float a = dwb[c];
#pragma unroll
      for (int dy = 0; dy < 3; ++dy) {
        int yy = row + dy - 1;
        if (yy < 0 || yy >= 64) continue;
        const float* rp = ip + yy*64;
#pragma unroll
        for (int dx = 0; dx < 3; ++dx) {
          int xx = lane + dx - 1;
          float tv = (xx >= 0 && xx < 64) ? rp[xx] : 0.f;
          a += wc[dy*3+dx] * tv;
        }
      }
      if (which == 0) { q[j] = a; sq += a*a; }
      else if (which == 1) { k[j] = a; sk += a*a; }
      else v[j] = a;
    }
  }
  sqq[wv][lane] = sq; sqk[wv][lane] = sk;
  __syncthreads();
  float tsq = sqq[0][lane] + sqq[1][lane];
  float tsk = sqk[0][lane] + sqk[1][lane];
  float tq = temp[h] * LOG2E / fmaxf(sqrtf(tsq), 1e-12f);
  float ik = 1.f            / fmaxf(sqrtf(tsk), 1e-12f);
  uint4 qo = make_uint4(cvtpk(q[0]*tq,q[1]*tq), cvtpk(q[2]*tq,q[3]*tq),
                        cvtpk(q[4]*tq,q[5]*tq), cvtpk(q[6]*tq,q[7]*tq));
  uint4 ko = make_uint4(cvtpk(k[0]*ik,k[1]*ik), cvtpk(k[2]*ik,k[3]*ik),
                        cvtpk(k[4]*ik,k[5]*ik), cvtpk(k[6]*ik,k[7]*ik));
  *(uint4*)(Qb + ((size_t)bh*HW + n)*16 + wv*8) = qo;
  *(uint4*)(Kb + ((size_t)bh*HW + n)*16 + wv*8) = ko;
#pragma unroll
  for (int j = 0; j < 8; ++j)
    Vtb[((size_t)bh*16 + wv*8 + j)*HW + n] = (ushort)(cvtpk(v[j], v[j]) & 0xffffu);
}

// ---------- K6: MFMA flash attention, software-pipelined, fully unrolled ----------
__global__ __launch_bounds__(256) void k_attn(const ushort* __restrict__ Qb,
                                              const ushort* __restrict__ Kb,
                                              const ushort* __restrict__ Vtb,
                                              float* __restrict__ part) {
  __shared__ ushort plds[4][2][32][32];   // [wave][dbuf][q][key]
  __shared__ float eplds[4][32][NPLANE];
  int blk = blockIdx.x;                // bh(6) x qt(32) x ks(8)
  int ks = blk & (KSPLIT-1);
  int qt = (blk >> 3) & 31;
  int bh = blk >> 8;
  int lane = threadIdx.x & 63;
  int wid  = threadIdx.x >> 6;
  int l31 = lane & 31;
  int lhi = lane >> 5;
  int qbase = qt*128 + wid*32;

  bf16x8 qf = *(const bf16x8*)(Qb + ((size_t)bh*HW + qbase + l31)*16 + lhi*8);

  const f32x16 z16 = {0,0,0,0,0,0,0,0,0,0,0,0,0,0,0,0};
  const short oneb = (short)0x3f80;
  const bf16x8 ones = {oneb,oneb,oneb,oneb,oneb,oneb,oneb,oneb};
  f32x4 acc0 = {0,0,0,0}, acc1 = {0,0,0,0};
  f32x4 accD0 = {0,0,0,0}, accD1 = {0,0,0,0};
  char* base = (char*)&plds[wid][0][0][0];
  int qr = lane & 15, gr = lane >> 4;
  int rdoff0 = qr*64 + 16*(gr ^ ((qr>>1)&3));
  int sw = (l31 >> 1) & 3;
  int wroff = l31*64 + 8*lhi;

  const ushort* Kbase = Kb + (size_t)bh*HW*16;
  const ushort* Vbase = Vtb + ((size_t)bh*16 + qr)*HW;
  int kbeg = ks * (HW/KSPLIT);
  constexpr int ITERS = (HW/KSPLIT)/32;   // 16

  bf16x8 kf = *(const bf16x8*)(Kbase + (size_t)(kbeg + l31)*16 + lhi*8);
  f32x16 st = __builtin_amdgcn_mfma_f32_32x32x16_bf16(kf, qf, z16, 0, 0, 0);

#pragma unroll
  for (int i = 0; i < ITERS-1; ++i) {
    int kk = kbeg + i*32;
    char* wb = base + (i & 1)*2048;
#pragma unroll
    for (int g4 = 0; g4 < 4; ++g4) {
      float e0 = fmaxf(fexp2(st[4*g4+0]), 1.f);
      float e1 = fmaxf(fexp2(st[4*g4+1]), 1.f);
      float e2 = fmaxf(fexp2(st[4*g4+2]), 1.f);
      float e3 = fmaxf(fexp2(st[4*g4+3]), 1.f);
      uint2 pk;
      pk.x = cvtpk(e0, e1);
      pk.y = cvtpk(e2, e3);
      *(uint2*)(wb + wroff + 16*(g4 ^ sw)) = pk;
    }
    kf = *(const bf16x8*)(Kbase + (size_t)(kk + 32 + l31)*16 + lhi*8);
    f32x16 stn = __builtin_amdgcn_mfma_f32_32x32x16_bf16(kf, qf, z16, 0, 0, 0);
    bf16x8 vf = *(const bf16x8*)(Vbase + kk + 8*gr);
    bf16x8 pa0 = *(const bf16x8*)(wb + rdoff0);
    bf16x8 pa1 = *(const bf16x8*)(wb + 1024 + rdoff0);
    acc0  = __builtin_amdgcn_mfma_f32_16x16x32_bf16(pa0, vf, acc0, 0, 0, 0);
    acc1  = __builtin_amdgcn_mfma_f32_16x16x32_bf16(pa1, vf, acc1, 0, 0, 0);
    accD0 = __builtin_amdgcn_mfma_f32_16x16x32_bf16(pa0, ones, accD0, 0, 0, 0);
    accD1 = __builtin_amdgcn_mfma_f32_16x16x32_bf16(pa1, ones, accD1, 0, 0, 0);
    st = stn;
  }
  {
    int kk = kbeg + (ITERS-1)*32;
    char* wb = base + ((ITERS-1) & 1)*2048;
#pragma unroll
    for (int g4 = 0; g4 < 4; ++g4) {
      float e0 = fmaxf(fexp2(st[4*g4+0]), 1.f);
      float e1 = fmaxf(fexp2(st[4*g4+1]), 1.f);
      float e2 = fmaxf(fexp2(st[4*g4+2]), 1.f);
      float e3 = fmaxf(fexp2(st[4*g4+3]), 1.f);
      uint2 pk;
      pk.x = cvtpk(e0, e1);
      pk.y = cvtpk(e2, e3);
      *(uint2*)(wb + wroff + 16*(g4 ^ sw)) = pk;
    }
    bf16x8 vf = *(const bf16x8*)(Vbase + kk + 8*gr);
    bf16x8 pa0 = *(const bf16x8*)(wb + rdoff0);
    bf16x8 pa1 = *(const bf16x8*)(wb + 1024 + rdoff0);
    acc0  = __builtin_amdgcn_mfma_f32_16x16x32_bf16(pa0, vf, acc0, 0, 0, 0);
    acc1  = __builtin_amdgcn_mfma_f32_16x16x32_bf16(pa1, vf, acc1, 0, 0, 0);
    accD0 = __builtin_amdgcn_mfma_f32_16x16x32_bf16(pa0, ones, accD0, 0, 0, 0);
    accD1 = __builtin_amdgcn_mfma_f32_16x16x32_bf16(pa1, ones, accD1, 0, 0, 0);
  }

#pragma unroll
  for (int r = 0; r < 4; ++r) {
    eplds[wid][gr*4 + r][qr]      = acc0[r];
    eplds[wid][gr*4 + 16 + r][qr] = acc1[r];
  }
  if (qr == 0) {
#pragma unroll
    for (int r = 0; r < 4; ++r) {
      eplds[wid][gr*4 + r][16]      = accD0[r];
      eplds[wid][gr*4 + 16 + r][16] = accD1[r];
    }
  }
  __syncthreads();
  size_t pb = ((size_t)(ks*6 + bh))*NPLANE;
  for (int i = threadIdx.x; i < 4*32*NPLANE; i += 256) {
    int w = i / (32*NPLANE);
    int rem = i - w*(32*NPLANE);
    int cc = rem >> 5;
    int q = rem & 31;
    part[(pb + cc)*HW + qt*128 + w*32 + q] = eplds[w][q][cc];
  }
}

// ---------- K7: ksplit-reduce + SE/attn combine + LN2, per (pixel, head) ----------
__global__ __launch_bounds__(192) void k_combR(const float* __restrict__ part,
                                               const float* __restrict__ x,
                                               const float* __restrict__ lw1,
                                               const float* __restrict__ lb1,
                                               const float* __restrict__ se,
                                               const float* __restrict__ beta,
                                               const float* __restrict__ beta2,
                                               const float* __restrict__ lw2,
                                               const float* __restrict__ lb2,
                                               float* __restrict__ y1,
                                               float* __restrict__ tn) {
  __shared__ float r1[3][64], r2[3][64], r3[3][64], r4[3][64];
  int t = threadIdx.x;
  int px = t & 63, h = t >> 6;          // 3 waves = 3 heads
  int gp = blockIdx.x*64 + px;
  int b = gp >> 12, n = gp & 4095;
  int bh = b*NH + h;

  float acc[16] = {0,0,0,0,0,0,0,0,0,0,0,0,0,0,0,0};
  float den = 0.f;
#pragma unroll
  for (int ks = 0; ks < KSPLIT; ++ks) {
    const float* pl = part + ((size_t)((ks*6+bh)*NPLANE))*HW + n;
#pragma unroll
    for (int cc = 0; cc < 16; ++cc) acc[cc] += pl[(size_t)cc*HW];
    den += pl[(size_t)16*HW];
  }
  const float* xp = x + ((size_t)b*CH + h*16)*HW + n;
  float xv[16]; float s = 0.f, ssum = 0.f;
#pragma unroll
  for (int cc = 0; cc < 16; ++cc) {
    float vv = xp[(size_t)cc*HW];
    xv[cc] = vv; s += vv; ssum += vv*vv;
  }
  r1[h][px] = s; r2[h][px] = ssum;
  __syncthreads();
  float stot = r1[0][px]+r1[1][px]+r1[2][px];
  float sstot = r2[0][px]+r2[1][px]+r2[2][px];
  float mu = stot*(1.f/CH);
  float rs = rsqrtf(sstot*(1.f/CH) - mu*mu + 1e-6f);
  float inv = 1.f / den;
  float yv[16]; float s2 = 0.f, ss2 = 0.f;
#pragma unroll
  for (int cc = 0; cc < 16; ++cc) {
    int c = h*16 + cc;
    float xnv = lw1[c]*((xv[cc]-mu)*rs) + lb1[c];
    float y = xv[cc] + xnv*se[b*CH+c]*beta[c] + acc[cc]*inv*beta2[c];
    yv[cc] = y; s2 += y; ss2 += y*y;
  }
  r3[h][px] = s2; r4[h][px] = ss2;
  __syncthreads();
  float s2t = r3[0][px]+r3[1][px]+r3[2][px];
  float ss2t = r4[0][px]+r4[1][px]+r4[2][px];
  float mu2 = s2t*(1.f/CH);
  float rs2 = rsqrtf(ss2t*(1.f/CH) - mu2*mu2 + 1e-6f);
  float* yp = y1 + ((size_t)b*CH + h*16)*HW + n;
  float* tp = tn + ((size_t)b*CH + h*16)*HW + n;
#pragma unroll
  for (int cc = 0; cc < 16; ++cc) {
    int c = h*16 + cc;
    yp[(size_t)cc*HW] = yv[cc];
    tp[(size_t)cc*HW] = lw2[c]*((yv[cc]-mu2)*rs2) + lb2[c];
  }
}

// ---------- K8b: conv4 + gate ----------
__global__ __launch_bounds__(256) void k_gate(const float* __restrict__ tn,
                                              const float* __restrict__ w4,
                                              const float* __restrict__ b4,
                                              float* __restrict__ g) {
  int blk = blockIdx.x;              // b(2) x o(48) x strip(8)
  int strip = blk & 7;
  int o = (blk >> 3) % CH;
  int b = blk / (CH*8);
  const float* w1 = w4 + (size_t)o*CH;
  const float* w2 = w4 + (size_t)(o+CH)*CH;
  const float* tb = tn + (size_t)b*CH*HW;
  float bb1 = b4[o], bb2 = b4[o+CH];
  float* gp = g + ((size_t)b*CH + o)*HW;
  for (int p = strip*512 + threadIdx.x; p < strip*512 + 512; p += 256) {
    float f1 = bb1, f2 = bb2;
#pragma unroll
    for (int c = 0; c < CH; ++c) {
      float xv = tb[(size_t)c*HW + p];
      f1 += w1[c]*xv; f2 += w2[c]*xv;
    }
    gp[p] = f1*f2;
  }
}

// ---------- K8c: conv5 + residual ----------
__global__ __launch_bounds__(256) void k_conv5(const float* __restrict__ g,
                                               const float* __restrict__ w5,
                                               const float* __restrict__ b5,
                                               const float* __restrict__ gamma,
                                               const float* __restrict__ y1,
                                               float* __restrict__ out) {
  int blk = blockIdx.x;              // b(2) x o(48) x strip(8)
  int strip = blk & 7;
  int o = (blk >> 3) % CH;
  int b = blk / (CH*8);
  const float* wrow = w5 + (size_t)o*CH;
  const float* gb = g + (size_t)b*CH*HW;
  float bo = b5[o], gm = gamma[o];
  const float* yp = y1 + ((size_t)b*CH + o)*HW;
  float* op = out + ((size_t)b*CH + o)*HW;
  for (int p = strip*512 + threadIdx.x; p < strip*512 + 512; p += 256) {
    float a = bo;
#pragma unroll
    for (int c = 0; c < CH; ++c) a += wrow[c] * gb[(size_t)c*HW + p];
    op[p] = yp[p] + a*gm;
  }
}

extern "C" void kernel_launch(void* const* d_in, const int* in_sizes, int n_in,
                              void* d_out, int out_size, void* d_ws, size_t ws_size,
                              hipStream_t stream) {
  const float* x      = (const float*)d_in[0];
  const float* ln1_w  = (const float*)d_in[1];
  const float* ln1_b  = (const float*)d_in[2];
  const float* qkv_w  = (const float*)d_in[3];
  const float* qkv_b  = (const float*)d_in[4];
  const float* dw_w   = (const float*)d_in[5];
  const float* dw_b   = (const float*)d_in[6];
  const float* temp   = (const float*)d_in[7];
  const float* ca_w1  = (const float*)d_in[8];
  const float* ca_b1  = (const float*)d_in[9];
  const float* ca_w2  = (const float*)d_in[10];
  const float* ca_b2  = (const float*)d_in[11];
  const float* beta   = (const float*)d_in[12];
  const float* beta2  = (const float*)d_in[13];
  const float* ln2_w  = (const float*)d_in[14];
  const float* ln2_b  = (const float*)d_in[15];
  const float* conv4_w= (const float*)d_in[16];
  const float* conv4_b= (const float*)d_in[17];
  const float* conv5_w= (const float*)d_in[18];
  const float* conv5_b= (const float*)d_in[19];
  const float* gamma  = (const float*)d_in[20];

  float* ws   = (float*)d_ws;
  float* bp   = ws + OFF_BP;
  float* se   = ws + OFF_SE;
  ushort* Qb  = (ushort*)(ws + OFF_QB);
  ushort* Kb  = (ushort*)(ws + OFF_KB);
  ushort* Vtb = (ushort*)(ws + OFF_VT);
  float* y1   = ws + OFF_Y1;
  float* tn   = ws + OFF_TN;
  float* g    = ws + OFF_G;
  float* qkv1 = ws + OFF_QKV1;
  float* part = ws + OFF_PART;
  float* out  = (float*)d_out;

  k_lnconv<<<256, 256, 0, stream>>>(x, ln1_w, ln1_b, qkv_w, qkv_b, qkv1, bp);
  k_se    <<<1,   128, 0, stream>>>(bp, ca_w1, ca_b1, ca_w2, ca_b2, se);
  k_dwprep<<<384, 128, 0, stream>>>(qkv1, dw_w, dw_b, temp, Qb, Kb, Vtb);
  k_attn  <<<1536,256, 0, stream>>>(Qb, Kb, Vtb, part);
  k_combR <<<128, 192, 0, stream>>>(part, x, ln1_w, ln1_b, se, beta, beta2,
                                    ln2_w, ln2_b, y1, tn);
  k_gate  <<<768, 256, 0, stream>>>(tn, conv4_w, conv4_b, g);
  k_conv5 <<<768, 256, 0, stream>>>(g, conv5_w, conv5_b, gamma, y1, out);
}

// Round 6
// 96.287 us; speedup vs baseline: 4.2744x; 1.2424x over previous
//
#include <hip/hip_runtime.h>
#include <cstddef>
#include <cmath>

#define BN 2
#define CH 48
#define HW 4096
#define NH 3
#define QC 144      // 3*CH
#define RR 3        // CH/16
#define KSPLIT 4
#define NPLANE 17   // 16 acc + 1 denom planes per (ks,bh)
#define LOG2E 1.4426950408889634f

typedef __attribute__((ext_vector_type(8))) short bf16x8;
typedef __attribute__((ext_vector_type(16))) float f32x16;
typedef __attribute__((ext_vector_type(4))) float f32x4;

// ---- workspace layout (floats) ----
constexpr size_t OFF_BP  = 0;                       // 256*48 = 12288
constexpr size_t OFF_QB  = 12288;                   // 98304 (bf16 [bh][n][16])
constexpr size_t OFF_KB  = OFF_QB + 98304;
constexpr size_t OFF_VT  = OFF_KB + 98304;
constexpr size_t OFF_Y1  = OFF_VT + 98304;          // 393216
constexpr size_t OFF_TN  = OFF_Y1 + 393216;
constexpr size_t OFF_QKV1= OFF_TN + 393216;         // 1179648
constexpr size_t OFF_PART= OFF_QKV1 + 1179648;      // 4*6*17*4096 = 1671168

static __device__ __forceinline__ unsigned cvtpk(float lo, float hi) {
  unsigned r;
  asm("v_cvt_pk_bf16_f32 %0, %1, %2" : "=v"(r) : "v"(lo), "v"(hi));
  return r;
}

static __device__ __forceinline__ float fexp2(float x) {
#if __has_builtin(__builtin_amdgcn_exp2f)
  return __builtin_amdgcn_exp2f(x);
#else
  float r; asm("v_exp_f32 %0, %1" : "=v"(r) : "v"(x)); return r;
#endif
}

// ---------- K1: fused LN1 + pool-partial + conv1x1(48->144) ----------
__global__ __launch_bounds__(256) void k_lnconv(const float* __restrict__ x,
                                                const float* __restrict__ lw,
                                                const float* __restrict__ lb,
                                                const float* __restrict__ w,
                                                const float* __restrict__ bias,
                                                float* __restrict__ qkv1,
                                                float* __restrict__ bpool) {
  __shared__ float xt[CH][33];
  __shared__ float sums[8][32], sqs[8][32];
  int blk = blockIdx.x;          // b*128 + tile
  int b = blk >> 7, tile = blk & 127;
  int t = threadIdx.x;
  int px = t & 31, cq = t >> 5;  // 8 channel groups of 6
  int n0 = tile*32;
  const float* xb = x + (size_t)b*CH*HW + n0 + px;
  float v[6]; float s = 0.f, ss = 0.f;
#pragma unroll
  for (int j = 0; j < 6; ++j) {
    float vv = xb[(size_t)(cq*6 + j)*HW];
    v[j] = vv; s += vv; ss += vv*vv;
  }
  sums[cq][px] = s; sqs[cq][px] = ss;
  __syncthreads();
  float stot = 0.f, sstot = 0.f;
#pragma unroll
  for (int i = 0; i < 8; ++i) { stot += sums[i][px]; sstot += sqs[i][px]; }
  float mu = stot * (1.f/CH);
  float rs = rsqrtf(sstot*(1.f/CH) - mu*mu + 1e-6f);
#pragma unroll
  for (int j = 0; j < 6; ++j) {
    int c = cq*6 + j;
    xt[c][px] = lw[c]*((v[j]-mu)*rs) + lb[c];
  }
  __syncthreads();
  if (t < CH) {
    float a = 0.f;
#pragma unroll
    for (int p2 = 0; p2 < 32; ++p2) a += xt[t][p2];
    bpool[(size_t)blk*CH + t] = a;
  }
  float xv[CH];
#pragma unroll
  for (int c = 0; c < CH; ++c) xv[c] = xt[c][px];
  float* op = qkv1 + (size_t)b*QC*HW + n0 + px;
#pragma unroll 3
  for (int oi = 0; oi < 18; ++oi) {
    int o = cq*18 + oi;
    float a = bias[o];
#pragma unroll
    for (int c = 0; c < CH; ++c) a += w[(size_t)o*CH + c]*xv[c];
    op[(size_t)o*HW] = a;
  }
}

// ---------- K2: fused depthwise3x3 + token norm/pack (4 waves, 4ch groups) ----------
__global__ __launch_bounds__(256) void k_dwprep(const float* __restrict__ qkv1,
                                                const float* __restrict__ dww,
                                                const float* __restrict__ dwb,
                                                const float* __restrict__ temp,
                                                ushort* __restrict__ Qb,
                                                ushort* __restrict__ Kb,
                                                ushort* __restrict__ Vtb) {
  __shared__ float sqq[4][64], sqk[4][64];
  int blk = blockIdx.x;               // bh*64 + row
  int row = blk & 63, bh = blk >> 6;
  int b = bh / NH, h = bh % NH;
  int lane = threadIdx.x & 63, wv = threadIdx.x >> 6;   // wv 0..3
  int n = row*64 + lane;
  const float* base = qkv1 + (size_t)b*QC*HW;

  float q[4], k[4], v[4];
  float sq = 0.f, sk = 0.f;
#pragma unroll
  for (int j = 0; j < 4; ++j) {
    int cc = wv*4 + j;
#pragma unroll
    for (int which = 0; which < 3; ++which) {
      int c = which*48 + h*16 + cc;
      const float* ip = base + (size_t)c*HW;
      const float* wc = dww + (size_t)c*9;
      float a = dwb[c];
#pragma unroll
      for (int dy = 0; dy < 3; ++dy) {
        int yy = row + dy - 1;
        if (yy < 0 || yy >= 64) continue;
        const float* rp = ip + yy*64;
#pragma unroll
        for (int dx = 0; dx < 3; ++dx) {
          int xx = lane + dx - 1;
          float tv = (xx >= 0 && xx < 64) ? rp[xx] : 0.f;
          a += wc[dy*3+dx] * tv;
        }
      }
      if (which == 0) { q[j] = a; sq += a*a; }
      else if (which == 1) { k[j] = a; sk += a*a; }
      else v[j] = a;
    }
  }
  sqq[wv][lane] = sq; sqk[wv][lane] = sk;
  __syncthreads();
  float tsq = sqq[0][lane]+sqq[1][lane]+sqq[2][lane]+sqq[3][lane];
  float tsk = sqk[0][lane]+sqk[1][lane]+sqk[2][lane]+sqk[3][lane];
  float tq = temp[h] * LOG2E / fmaxf(sqrtf(tsq), 1e-12f);
  float ik = 1.f            / fmaxf(sqrtf(tsk), 1e-12f);
  uint2 qo, ko;
  qo.x = cvtpk(q[0]*tq, q[1]*tq); qo.y = cvtpk(q[2]*tq, q[3]*tq);
  ko.x = cvtpk(k[0]*ik, k[1]*ik); ko.y = cvtpk(k[2]*ik, k[3]*ik);
  *(uint2*)(Qb + ((size_t)bh*HW + n)*16 + wv*4) = qo;
  *(uint2*)(Kb + ((size_t)bh*HW + n)*16 + wv*4) = ko;
#pragma unroll
  for (int j = 0; j < 4; ++j)
    Vtb[((size_t)bh*16 + wv*4 + j)*HW + n] = (ushort)(cvtpk(v[j], v[j]) & 0xffffu);
}

// ---------- K3: MFMA flash attention, software-pipelined ----------
__global__ __launch_bounds__(256) void k_attn(const ushort* __restrict__ Qb,
                                              const ushort* __restrict__ Kb,
                                              const ushort* __restrict__ Vtb,
                                              float* __restrict__ part) {
  __shared__ ushort plds[4][2][32][32];   // [wave][dbuf][q][key]
  __shared__ float eplds[4][32][NPLANE];
  int blk = blockIdx.x;                // bh(6) x qt(32) x ks(4)
  int ks = blk & (KSPLIT-1);
  int qt = (blk >> 2) & 31;
  int bh = blk >> 7;
  int lane = threadIdx.x & 63;
  int wid  = threadIdx.x >> 6;
  int l31 = lane & 31;
  int lhi = lane >> 5;
  int qbase = qt*128 + wid*32;

  bf16x8 qf = *(const bf16x8*)(Qb + ((size_t)bh*HW + qbase + l31)*16 + lhi*8);

  const f32x16 z16 = {0,0,0,0,0,0,0,0,0,0,0,0,0,0,0,0};
  const short oneb = (short)0x3f80;
  const bf16x8 ones = {oneb,oneb,oneb,oneb,oneb,oneb,oneb,oneb};
  f32x4 acc0 = {0,0,0,0}, acc1 = {0,0,0,0};
  f32x4 accD0 = {0,0,0,0}, accD1 = {0,0,0,0};
  char* base = (char*)&plds[wid][0][0][0];
  int qr = lane & 15, gr = lane >> 4;
  int rdoff0 = qr*64 + 16*(gr ^ ((qr>>1)&3));
  int sw = (l31 >> 1) & 3;
  int wroff = l31*64 + 8*lhi;

  const ushort* Kbase = Kb + (size_t)bh*HW*16;
  const ushort* Vbase = Vtb + ((size_t)bh*16 + qr)*HW;
  int kbeg = ks * (HW/KSPLIT);
  constexpr int ITERS = (HW/KSPLIT)/32;   // 32

  bf16x8 kf = *(const bf16x8*)(Kbase + (size_t)(kbeg + l31)*16 + lhi*8);
  f32x16 st = __builtin_amdgcn_mfma_f32_32x32x16_bf16(kf, qf, z16, 0, 0, 0);

#pragma unroll 2
  for (int i = 0; i < ITERS-1; ++i) {
    int kk = kbeg + i*32;
    char* wb = base + (i & 1)*2048;
#pragma unroll
    for (int g4 = 0; g4 < 4; ++g4) {
      float e0 = fmaxf(fexp2(st[4*g4+0]), 1.f);
      float e1 = fmaxf(fexp2(st[4*g4+1]), 1.f);
      float e2 = fmaxf(fexp2(st[4*g4+2]), 1.f);
      float e3 = fmaxf(fexp2(st[4*g4+3]), 1.f);
      uint2 pk;
      pk.x = cvtpk(e0, e1);
      pk.y = cvtpk(e2, e3);
      *(uint2*)(wb + wroff + 16*(g4 ^ sw)) = pk;
    }
    kf = *(const bf16x8*)(Kbase + (size_t)(kk + 32 + l31)*16 + lhi*8);
    f32x16 stn = __builtin_amdgcn_mfma_f32_32x32x16_bf16(kf, qf, z16, 0, 0, 0);
    bf16x8 vf = *(const bf16x8*)(Vbase + kk + 8*gr);
    bf16x8 pa0 = *(const bf16x8*)(wb + rdoff0);
    bf16x8 pa1 = *(const bf16x8*)(wb + 1024 + rdoff0);
    acc0  = __builtin_amdgcn_mfma_f32_16x16x32_bf16(pa0, vf, acc0, 0, 0, 0);
    acc1  = __builtin_amdgcn_mfma_f32_16x16x32_bf16(pa1, vf, acc1, 0, 0, 0);
    accD0 = __builtin_amdgcn_mfma_f32_16x16x32_bf16(pa0, ones, accD0, 0, 0, 0);
    accD1 = __builtin_amdgcn_mfma_f32_16x16x32_bf16(pa1, ones, accD1, 0, 0, 0);
    st = stn;
  }
  {
    int kk = kbeg + (ITERS-1)*32;
    char* wb = base + ((ITERS-1) & 1)*2048;
#pragma unroll
    for (int g4 = 0; g4 < 4; ++g4) {
      float e0 = fmaxf(fexp2(st[4*g4+0]), 1.f);
      float e1 = fmaxf(fexp2(st[4*g4+1]), 1.f);
      float e2 = fmaxf(fexp2(st[4*g4+2]), 1.f);
      float e3 = fmaxf(fexp2(st[4*g4+3]), 1.f);
      uint2 pk;
      pk.x = cvtpk(e0, e1);
      pk.y = cvtpk(e2, e3);
      *(uint2*)(wb + wroff + 16*(g4 ^ sw)) = pk;
    }
    bf16x8 vf = *(const bf16x8*)(Vbase + kk + 8*gr);
    bf16x8 pa0 = *(const bf16x8*)(wb + rdoff0);
    bf16x8 pa1 = *(const bf16x8*)(wb + 1024 + rdoff0);
    acc0  = __builtin_amdgcn_mfma_f32_16x16x32_bf16(pa0, vf, acc0, 0, 0, 0);
    acc1  = __builtin_amdgcn_mfma_f32_16x16x32_bf16(pa1, vf, acc1, 0, 0, 0);
    accD0 = __builtin_amdgcn_mfma_f32_16x16x32_bf16(pa0, ones, accD0, 0, 0, 0);
    accD1 = __builtin_amdgcn_mfma_f32_16x16x32_bf16(pa1, ones, accD1, 0, 0, 0);
  }

#pragma unroll
  for (int r = 0; r < 4; ++r) {
    eplds[wid][gr*4 + r][qr]      = acc0[r];
    eplds[wid][gr*4 + 16 + r][qr] = acc1[r];
  }
  if (qr == 0) {
#pragma unroll
    for (int r = 0; r < 4; ++r) {
      eplds[wid][gr*4 + r][16]      = accD0[r];
      eplds[wid][gr*4 + 16 + r][16] = accD1[r];
    }
  }
  __syncthreads();
  size_t pb = ((size_t)(ks*6 + bh))*NPLANE;
  for (int i = threadIdx.x; i < 4*32*NPLANE; i += 256) {
    int w = i / (32*NPLANE);
    int rem = i - w*(32*NPLANE);
    int cc = rem >> 5;
    int q = rem & 31;
    part[(pb + cc)*HW + qt*128 + w*32 + q] = eplds[w][q][cc];
  }
}

// ---------- K4: SE-MLP + ksplit-reduce + combine + LN2, 32-px blocks ----------
__global__ __launch_bounds__(192) void k_combR(const float* __restrict__ part,
                                               const float* __restrict__ x,
                                               const float* __restrict__ lw1,
                                               const float* __restrict__ lb1,
                                               const float* __restrict__ bpool,
                                               const float* __restrict__ w1,
                                               const float* __restrict__ b1,
                                               const float* __restrict__ w2,
                                               const float* __restrict__ b2,
                                               const float* __restrict__ beta,
                                               const float* __restrict__ beta2,
                                               const float* __restrict__ lw2,
                                               const float* __restrict__ lb2,
                                               float* __restrict__ y1,
                                               float* __restrict__ tn) {
  __shared__ float sepm[CH][4];
  __shared__ float pmL[CH];
  __shared__ float yrL[4];
  __shared__ float seL[CH];
  __shared__ float r1[6][32], r2[6][32], r3[6][32], r4[6][32];
  int t = threadIdx.x;
  int px = t & 31, g6 = t >> 5;        // 6 groups: (head, half)
  int h = g6 >> 1, half = g6 & 1;
  int c0 = h*16 + half*8;
  int gp = blockIdx.x*32 + px;
  int b = gp >> 12, n = gp & 4095;
  int bh = b*NH + h;

  // SE MLP (block-redundant, bpool is L2/L3-hot)
  {
    int c = t >> 2, j = t & 3;
    const float* bp = bpool + (size_t)(b*128 + j*32)*CH + c;
    float a = 0.f;
#pragma unroll 8
    for (int i = 0; i < 32; ++i) a += bp[(size_t)i*CH];
    sepm[c][j] = a;
  }
  __syncthreads();
  if (t < CH) pmL[t] = (sepm[t][0]+sepm[t][1]+sepm[t][2]+sepm[t][3]) * (1.f/HW);
  __syncthreads();
  if (t < RR) {
    float a = b1[t];
    for (int c = 0; c < CH; ++c) a += w1[t*CH+c]*pmL[c];
    yrL[t] = fmaxf(a, 0.f);
  }
  __syncthreads();
  if (t < CH) {
    float a = b2[t];
    for (int r = 0; r < RR; ++r) a += w2[t*RR+r]*yrL[r];
    seL[t] = 1.f/(1.f+__expf(-a));
  }

  // ksplit reduce (8 channels + den per thread)
  float acc[8] = {0,0,0,0,0,0,0,0};
  float den = 0.f;
#pragma unroll
  for (int ks = 0; ks < KSPLIT; ++ks) {
    const float* pl = part + ((size_t)((ks*6+bh)*NPLANE + half*8))*HW + n;
#pragma unroll
    for (int cc = 0; cc < 8; ++cc) acc[cc] += pl[(size_t)cc*HW];
    den += pl[(size_t)(16 - half*8)*HW];
  }
  // LN1 stats on x
  const float* xp = x + ((size_t)b*CH + c0)*HW + n;
  float xv[8]; float s = 0.f, ssum = 0.f;
#pragma unroll
  for (int cc = 0; cc < 8; ++cc) {
    float vv = xp[(size_t)cc*HW];
    xv[cc] = vv; s += vv; ssum += vv*vv;
  }
  r1[g6][px] = s; r2[g6][px] = ssum;
  __syncthreads();
  float stot = 0.f, sstot = 0.f;
#pragma unroll
  for (int i = 0; i < 6; ++i) { stot += r1[i][px]; sstot += r2[i][px]; }
  float mu = stot*(1.f/CH);
  float rs = rsqrtf(sstot*(1.f/CH) - mu*mu + 1e-6f);
  float inv = 1.f / den;
  float yv[8]; float s2 = 0.f, ss2 = 0.f;
#pragma unroll
  for (int cc = 0; cc < 8; ++cc) {
    int c = c0 + cc;
    float xnv = lw1[c]*((xv[cc]-mu)*rs) + lb1[c];
    float y = xv[cc] + xnv*seL[c]*beta[c] + acc[cc]*inv*beta2[c];
    yv[cc] = y; s2 += y; ss2 += y*y;
  }
  r3[g6][px] = s2; r4[g6][px] = ss2;
  __syncthreads();
  float s2t = 0.f, ss2t = 0.f;
#pragma unroll
  for (int i = 0; i < 6; ++i) { s2t += r3[i][px]; ss2t += r4[i][px]; }
  float mu2 = s2t*(1.f/CH);
  float rs2 = rsqrtf(ss2t*(1.f/CH) - mu2*mu2 + 1e-6f);
  float* yp = y1 + ((size_t)b*CH + c0)*HW + n;
  float* tp = tn + ((size_t)b*CH + c0)*HW + n;
#pragma unroll
  for (int cc = 0; cc < 8; ++cc) {
    int c = c0 + cc;
    yp[(size_t)cc*HW] = yv[cc];
    tp[(size_t)cc*HW] = lw2[c]*((yv[cc]-mu2)*rs2) + lb2[c];
  }
}

// ---------- K5: fused FFN: conv4 -> gate -> conv5 -> residual ----------
// 64-px tile, 4 waves; wave owns 12 wave-uniform output channels (weights in SGPRs).
__global__ __launch_bounds__(256) void k_ffn(const float* __restrict__ tn,
                                             const float* __restrict__ w4,
                                             const float* __restrict__ b4,
                                             const float* __restrict__ w5,
                                             const float* __restrict__ b5,
                                             const float* __restrict__ gamma,
                                             const float* __restrict__ y1,
                                             float* __restrict__ out) {
  __shared__ float xt[CH][65];
  __shared__ float gt[CH][65];
  int blk = blockIdx.x;     // b*64 + tile
  int b = blk >> 6, tile = blk & 63;
  int n0 = tile*64;
  int lane = threadIdx.x & 63, wv = threadIdx.x >> 6;
  const float* tb = tn + (size_t)b*CH*HW + n0;
#pragma unroll
  for (int j = 0; j < 12; ++j) {
    int c = wv*12 + j;
    xt[c][lane] = tb[(size_t)c*HW + lane];
  }
  __syncthreads();
  float tcol[CH];
#pragma unroll
  for (int c = 0; c < CH; ++c) tcol[c] = xt[c][lane];
#pragma unroll 2
  for (int oi = 0; oi < 12; ++oi) {
    int o = wv*12 + oi;
    float f1 = b4[o], f2 = b4[o+CH];
#pragma unroll
    for (int c = 0; c < CH; ++c) {
      f1 += w4[(size_t)o*CH + c]*tcol[c];
      f2 += w4[(size_t)(o+CH)*CH + c]*tcol[c];
    }
    gt[o][lane] = f1*f2;
  }
  __syncthreads();
  float gcol[CH];
#pragma unroll
  for (int c = 0; c < CH; ++c) gcol[c] = gt[c][lane];
  const float* yp = y1 + (size_t)b*CH*HW + n0;
  float* op = out + (size_t)b*CH*HW + n0;
#pragma unroll 2
  for (int oi = 0; oi < 12; ++oi) {
    int o = wv*12 + oi;
    float a = b5[o];
#pragma unroll
    for (int c = 0; c < CH; ++c) a += w5[(size_t)o*CH + c]*gcol[c];
    op[(size_t)o*HW + lane] = yp[(size_t)o*HW + lane] + a*gamma[o];
  }
}

extern "C" void kernel_launch(void* const* d_in, const int* in_sizes, int n_in,
                              void* d_out, int out_size, void* d_ws, size_t ws_size,
                              hipStream_t stream) {
  const float* x      = (const float*)d_in[0];
  const float* ln1_w  = (const float*)d_in[1];
  const float* ln1_b  = (const float*)d_in[2];
  const float* qkv_w  = (const float*)d_in[3];
  const float* qkv_b  = (const float*)d_in[4];
  const float* dw_w   = (const float*)d_in[5];
  const float* dw_b   = (const float*)d_in[6];
  const float* temp   = (const float*)d_in[7];
  const float* ca_w1  = (const float*)d_in[8];
  const float* ca_b1  = (const float*)d_in[9];
  const float* ca_w2  = (const float*)d_in[10];
  const float* ca_b2  = (const float*)d_in[11];
  const float* beta   = (const float*)d_in[12];
  const float* beta2  = (const float*)d_in[13];
  const float* ln2_w  = (const float*)d_in[14];
  const float* ln2_b  = (const float*)d_in[15];
  const float* conv4_w= (const float*)d_in[16];
  const float* conv4_b= (const float*)d_in[17];
  const float* conv5_w= (const float*)d_in[18];
  const float* conv5_b= (const float*)d_in[19];
  const float* gamma  = (const float*)d_in[20];

  float* ws   = (float*)d_ws;
  float* bp   = ws + OFF_BP;
  ushort* Qb  = (ushort*)(ws + OFF_QB);
  ushort* Kb  = (ushort*)(ws + OFF_KB);
  ushort* Vtb = (ushort*)(ws + OFF_VT);
  float* y1   = ws + OFF_Y1;
  float* tn   = ws + OFF_TN;
  float* qkv1 = ws + OFF_QKV1;
  float* part = ws + OFF_PART;
  float* out  = (float*)d_out;

  k_lnconv<<<256, 256, 0, stream>>>(x, ln1_w, ln1_b, qkv_w, qkv_b, qkv1, bp);
  k_dwprep<<<384, 256, 0, stream>>>(qkv1, dw_w, dw_b, temp, Qb, Kb, Vtb);
  k_attn  <<<768, 256, 0, stream>>>(Qb, Kb, Vtb, part);
  k_combR <<<256, 192, 0, stream>>>(part, x, ln1_w, ln1_b, bp,
                                    ca_w1, ca_b1, ca_w2, ca_b2,
                                    beta, beta2, ln2_w, ln2_b, y1, tn);
  k_ffn   <<<128, 256, 0, stream>>>(tn, conv4_w, conv4_b, conv5_w, conv5_b,
                                    gamma, y1, out);
}

// Round 7
// 86.907 us; speedup vs baseline: 4.7357x; 1.1079x over previous
//
#include <hip/hip_runtime.h>
#include <cstddef>
#include <cmath>

#define BN 2
#define CH 48
#define HW 4096
#define NH 3
#define QC 144      // 3*CH
#define RR 3        // CH/16
#define KSPLIT 4
#define NPLANE 17   // 16 acc + 1 denom planes per (ks,bh)
#define LOG2E 1.4426950408889634f

typedef __attribute__((ext_vector_type(8))) short bf16x8;
typedef __attribute__((ext_vector_type(16))) float f32x16;
typedef __attribute__((ext_vector_type(4))) float f32x4;

// ---- workspace layout (floats) ----
constexpr size_t OFF_BP  = 0;                       // 256*48 = 12288
constexpr size_t OFF_QB  = 12288;                   // 98304 (bf16 [bh][n][16])
constexpr size_t OFF_KB  = OFF_QB + 98304;
constexpr size_t OFF_VT  = OFF_KB + 98304;
constexpr size_t OFF_QKV1= OFF_VT + 98304;          // 1179648
constexpr size_t OFF_PART= OFF_QKV1 + 1179648;      // 4*6*17*4096 = 1671168

static __device__ __forceinline__ unsigned cvtpk(float lo, float hi) {
  unsigned r;
  asm("v_cvt_pk_bf16_f32 %0, %1, %2" : "=v"(r) : "v"(lo), "v"(hi));
  return r;
}

static __device__ __forceinline__ float fexp2(float x) {
#if __has_builtin(__builtin_amdgcn_exp2f)
  return __builtin_amdgcn_exp2f(x);
#else
  float r; asm("v_exp_f32 %0, %1" : "=v"(r) : "v"(x)); return r;
#endif
}

// ---------- K1: fused LN1 + pool-partial + conv1x1(48->144) ----------
__global__ __launch_bounds__(256) void k_lnconv(const float* __restrict__ x,
                                                const float* __restrict__ lw,
                                                const float* __restrict__ lb,
                                                const float* __restrict__ w,
                                                const float* __restrict__ bias,
                                                float* __restrict__ qkv1,
                                                float* __restrict__ bpool) {
  __shared__ float xt[CH][33];
  __shared__ float sums[8][32], sqs[8][32];
  int blk = blockIdx.x;          // b*128 + tile
  int b = blk >> 7, tile = blk & 127;
  int t = threadIdx.x;
  int px = t & 31, cq = t >> 5;  // 8 channel groups of 6
  int n0 = tile*32;
  const float* xb = x + (size_t)b*CH*HW + n0 + px;
  float v[6]; float s = 0.f, ss = 0.f;
#pragma unroll
  for (int j = 0; j < 6; ++j) {
    float vv = xb[(size_t)(cq*6 + j)*HW];
    v[j] = vv; s += vv; ss += vv*vv;
  }
  sums[cq][px] = s; sqs[cq][px] = ss;
  __syncthreads();
  float stot = 0.f, sstot = 0.f;
#pragma unroll
  for (int i = 0; i < 8; ++i) { stot += sums[i][px]; sstot += sqs[i][px]; }
  float mu = stot * (1.f/CH);
  float rs = rsqrtf(sstot*(1.f/CH) - mu*mu + 1e-6f);
#pragma unroll
  for (int j = 0; j < 6; ++j) {
    int c = cq*6 + j;
    xt[c][px] = lw[c]*((v[j]-mu)*rs) + lb[c];
  }
  __syncthreads();
  if (t < CH) {
    float a = 0.f;
#pragma unroll
    for (int p2 = 0; p2 < 32; ++p2) a += xt[t][p2];
    bpool[(size_t)blk*CH + t] = a;
  }
  float xv[CH];
#pragma unroll
  for (int c = 0; c < CH; ++c) xv[c] = xt[c][px];
  float* op = qkv1 + (size_t)b*QC*HW + n0 + px;
#pragma unroll 3
  for (int oi = 0; oi < 18; ++oi) {
    int o = cq*18 + oi;
    float a = bias[o];
#pragma unroll
    for (int c = 0; c < CH; ++c) a += w[(size_t)o*CH + c]*xv[c];
    op[(size_t)o*HW] = a;
  }
}

// ---------- K2: fused depthwise3x3 + token norm/pack (4 waves, 4ch groups) ----------
__global__ __launch_bounds__(256) void k_dwprep(const float* __restrict__ qkv1,
                                                const float* __restrict__ dww,
                                                const float* __restrict__ dwb,
                                                const float* __restrict__ temp,
                                                ushort* __restrict__ Qb,
                                                ushort* __restrict__ Kb,
                                                ushort* __restrict__ Vtb) {
  __shared__ float sqq[4][64], sqk[4][64];
  int blk = blockIdx.x;               // bh*64 + row
  int row = blk & 63, bh = blk >> 6;
  int b = bh / NH, h = bh % NH;
  int lane = threadIdx.x & 63, wv = threadIdx.x >> 6;   // wv 0..3
  int n = row*64 + lane;
  const float* base = qkv1 + (size_t)b*QC*HW;

  float q[4], k[4], v[4];
  float sq = 0.f, sk = 0.f;
#pragma unroll
  for (int j = 0; j < 4; ++j) {
    int cc = wv*4 + j;
#pragma unroll
    for (int which = 0; which < 3; ++which) {
      int c = which*48 + h*16 + cc;
      const float* ip = base + (size_t)c*HW;
      const float* wc = dww + (size_t)c*9;
      float a = dwb[c];
#pragma unroll
      for (int dy = 0; dy < 3; ++dy) {
        int yy = row + dy - 1;
        if (yy < 0 || yy >= 64) continue;
        const float* rp = ip + yy*64;
#pragma unroll
        for (int dx = 0; dx < 3; ++dx) {
          int xx = lane + dx - 1;
          float tv = (xx >= 0 && xx < 64) ? rp[xx] : 0.f;
          a += wc[dy*3+dx] * tv;
        }
      }
      if (which == 0) { q[j] = a; sq += a*a; }
      else if (which == 1) { k[j] = a; sk += a*a; }
      else v[j] = a;
    }
  }
  sqq[wv][lane] = sq; sqk[wv][lane] = sk;
  __syncthreads();
  float tsq = sqq[0][lane]+sqq[1][lane]+sqq[2][lane]+sqq[3][lane];
  float tsk = sqk[0][lane]+sqk[1][lane]+sqk[2][lane]+sqk[3][lane];
  float tq = temp[h] * LOG2E / fmaxf(sqrtf(tsq), 1e-12f);
  float ik = 1.f            / fmaxf(sqrtf(tsk), 1e-12f);
  uint2 qo, ko;
  qo.x = cvtpk(q[0]*tq, q[1]*tq); qo.y = cvtpk(q[2]*tq, q[3]*tq);
  ko.x = cvtpk(k[0]*ik, k[1]*ik); ko.y = cvtpk(k[2]*ik, k[3]*ik);
  *(uint2*)(Qb + ((size_t)bh*HW + n)*16 + wv*4) = qo;
  *(uint2*)(Kb + ((size_t)bh*HW + n)*16 + wv*4) = ko;
#pragma unroll
  for (int j = 0; j < 4; ++j)
    Vtb[((size_t)bh*16 + wv*4 + j)*HW + n] = (ushort)(cvtpk(v[j], v[j]) & 0xffffu);
}

// ---------- K3: MFMA flash attention, skewed software pipeline ----------
// PV(i-1) reads P written one FULL iteration earlier; QK(i) MFMA + K/V loads
// sit between ds_write and ds_read to cover LDS latency.
#define PACK(stv, wbp) do {                                              \
  _Pragma("unroll")                                                      \
  for (int g4 = 0; g4 < 4; ++g4) {                                       \
    float e0 = fmaxf(fexp2((stv)[4*g4+0]), 1.f);                         \
    float e1 = fmaxf(fexp2((stv)[4*g4+1]), 1.f);                         \
    float e2 = fmaxf(fexp2((stv)[4*g4+2]), 1.f);                         \
    float e3 = fmaxf(fexp2((stv)[4*g4+3]), 1.f);                         \
    uint2 pk;                                                            \
    pk.x = cvtpk(e0, e1);                                                \
    pk.y = cvtpk(e2, e3);                                                \
    *(uint2*)((wbp) + wroff + 16*(g4 ^ sw)) = pk;                        \
  } } while (0)

__global__ __launch_bounds__(256) void k_attn(const ushort* __restrict__ Qb,
                                              const ushort* __restrict__ Kb,
                                              const ushort* __restrict__ Vtb,
                                              float* __restrict__ part) {
  __shared__ ushort plds[4][2][32][32];   // [wave][dbuf][q][key]
  __shared__ float eplds[4][32][NPLANE];
  int blk = blockIdx.x;                // bh(6) x qt(32) x ks(4)
  int ks = blk & (KSPLIT-1);
  int qt = (blk >> 2) & 31;
  int bh = blk >> 7;
  int lane = threadIdx.x & 63;
  int wid  = threadIdx.x >> 6;
  int l31 = lane & 31;
  int lhi = lane >> 5;
  int qbase = qt*128 + wid*32;

  bf16x8 qf = *(const bf16x8*)(Qb + ((size_t)bh*HW + qbase + l31)*16 + lhi*8);

  const f32x16 z16 = {0,0,0,0,0,0,0,0,0,0,0,0,0,0,0,0};
  const short oneb = (short)0x3f80;
  const bf16x8 ones = {oneb,oneb,oneb,oneb,oneb,oneb,oneb,oneb};
  f32x4 acc0 = {0,0,0,0}, acc1 = {0,0,0,0};
  f32x4 accD0 = {0,0,0,0}, accD1 = {0,0,0,0};
  char* base = (char*)&plds[wid][0][0][0];
  int qr = lane & 15, gr = lane >> 4;
  int rdoff0 = qr*64 + 16*(gr ^ ((qr>>1)&3));
  int sw = (l31 >> 1) & 3;
  int wroff = l31*64 + 8*lhi;

  const ushort* Kbase = Kb + (size_t)bh*HW*16;
  const ushort* Vbase = Vtb + ((size_t)bh*16 + qr)*HW;
  int kbeg = ks * (HW/KSPLIT);
  constexpr int ITERS = (HW/KSPLIT)/32;   // 32

  // prologue: S(0) -> pack into buf0
  bf16x8 kf = *(const bf16x8*)(Kbase + (size_t)(kbeg + l31)*16 + lhi*8);
  f32x16 st = __builtin_amdgcn_mfma_f32_32x32x16_bf16(kf, qf, z16, 0, 0, 0);
  PACK(st, base);

#pragma unroll 2
  for (int i = 1; i < ITERS; ++i) {
    // P fragments for PV(i-1): written one full iteration ago
    char* rb = base + ((i-1) & 1)*2048;
    bf16x8 pa0 = *(const bf16x8*)(rb + rdoff0);
    bf16x8 pa1 = *(const bf16x8*)(rb + 1024 + rdoff0);
    // QK(i) issued between the ds_read and its MFMA consumers
    kf = *(const bf16x8*)(Kbase + (size_t)(kbeg + i*32 + l31)*16 + lhi*8);
    f32x16 stn = __builtin_amdgcn_mfma_f32_32x32x16_bf16(kf, qf, z16, 0, 0, 0);
    bf16x8 vf = *(const bf16x8*)(Vbase + kbeg + (i-1)*32 + 8*gr);
    acc0  = __builtin_amdgcn_mfma_f32_16x16x32_bf16(pa0, vf, acc0, 0, 0, 0);
    acc1  = __builtin_amdgcn_mfma_f32_16x16x32_bf16(pa1, vf, acc1, 0, 0, 0);
    accD0 = __builtin_amdgcn_mfma_f32_16x16x32_bf16(pa0, ones, accD0, 0, 0, 0);
    accD1 = __builtin_amdgcn_mfma_f32_16x16x32_bf16(pa1, ones, accD1, 0, 0, 0);
    // pack S(i) -> buf(i&1), read next iteration
    PACK(stn, base + (i & 1)*2048);
  }
  {
    char* rb = base + ((ITERS-1) & 1)*2048;
    bf16x8 pa0 = *(const bf16x8*)(rb + rdoff0);
    bf16x8 pa1 = *(const bf16x8*)(rb + 1024 + rdoff0);
    bf16x8 vf = *(const bf16x8*)(Vbase + kbeg + (ITERS-1)*32 + 8*gr);
    acc0  = __builtin_amdgcn_mfma_f32_16x16x32_bf16(pa0, vf, acc0, 0, 0, 0);
    acc1  = __builtin_amdgcn_mfma_f32_16x16x32_bf16(pa1, vf, acc1, 0, 0, 0);
    accD0 = __builtin_amdgcn_mfma_f32_16x16x32_bf16(pa0, ones, accD0, 0, 0, 0);
    accD1 = __builtin_amdgcn_mfma_f32_16x16x32_bf16(pa1, ones, accD1, 0, 0, 0);
  }

#pragma unroll
  for (int r = 0; r < 4; ++r) {
    eplds[wid][gr*4 + r][qr]      = acc0[r];
    eplds[wid][gr*4 + 16 + r][qr] = acc1[r];
  }
  if (qr == 0) {
#pragma unroll
    for (int r = 0; r < 4; ++r) {
      eplds[wid][gr*4 + r][16]      = accD0[r];
      eplds[wid][gr*4 + 16 + r][16] = accD1[r];
    }
  }
  __syncthreads();
  size_t pb = ((size_t)(ks*6 + bh))*NPLANE;
  for (int i = threadIdx.x; i < 4*32*NPLANE; i += 256) {
    int w = i / (32*NPLANE);
    int rem = i - w*(32*NPLANE);
    int cc = rem >> 5;
    int q = rem & 31;
    part[(pb + cc)*HW + qt*128 + w*32 + q] = eplds[w][q][cc];
  }
}

// ---------- K4: tail — SE + ksplit-reduce + combine + LN2 + full FFN ----------
// 128 blocks x 384 thr; 64-px tiles; wave w owns channels w*8..w*8+8 (wave-
// uniform FFN weight rows -> scalar loads). y1 stays in registers; tn and the
// gate live only in LDS — no HBM round-trips.
__global__ __launch_bounds__(384) void k_tail(const float* __restrict__ part,
                                              const float* __restrict__ x,
                                              const float* __restrict__ lw1,
                                              const float* __restrict__ lb1,
                                              const float* __restrict__ bpool,
                                              const float* __restrict__ w1,
                                              const float* __restrict__ b1,
                                              const float* __restrict__ w2,
                                              const float* __restrict__ b2,
                                              const float* __restrict__ beta,
                                              const float* __restrict__ beta2,
                                              const float* __restrict__ lw2,
                                              const float* __restrict__ lb2,
                                              const float* __restrict__ w4,
                                              const float* __restrict__ b4,
                                              const float* __restrict__ w5,
                                              const float* __restrict__ b5,
                                              const float* __restrict__ gamma,
                                              float* __restrict__ out) {
  __shared__ float sepm[CH][4];
  __shared__ float pmL[CH];
  __shared__ float yrL[4];
  __shared__ float seL[CH];
  __shared__ float r1[6][64], r2[6][64], r3[6][64], r4[6][64];
  __shared__ float xt[CH][65];   // LN2 output
  __shared__ float gt[CH][65];   // gate output
  int t = threadIdx.x;
  int lane = t & 63, w = t >> 6;      // 6 waves
  int h = w >> 1;
  int c0 = w * 8;
  int qoff = (w & 1) * 8;
  int gp = blockIdx.x*64 + lane;
  int b = gp >> 12, n = gp & 4095;
  int bh = b*NH + h;

  // SE MLP (block-redundant; bpool is L2-hot)
  if (t < 192) {
    int c = t % CH, j = t / CH;
    const float* bp = bpool + (size_t)(b*128 + j*32)*CH + c;
    float a = 0.f;
#pragma unroll 8
    for (int i = 0; i < 32; ++i) a += bp[(size_t)i*CH];
    sepm[c][j] = a;
  }
  __syncthreads();
  if (t < CH) pmL[t] = (sepm[t][0]+sepm[t][1]+sepm[t][2]+sepm[t][3]) * (1.f/HW);
  __syncthreads();
  if (t < RR) {
    float a = b1[t];
    for (int c = 0; c < CH; ++c) a += w1[t*CH+c]*pmL[c];
    yrL[t] = fmaxf(a, 0.f);
  }
  __syncthreads();
  if (t < CH) {
    float a = b2[t];
    for (int r = 0; r < RR; ++r) a += w2[t*RR+r]*yrL[r];
    seL[t] = 1.f/(1.f+__expf(-a));
  }

  // ksplit reduce: 8 channels + den per thread
  float acc[8] = {0,0,0,0,0,0,0,0};
  float den = 0.f;
#pragma unroll
  for (int ks = 0; ks < KSPLIT; ++ks) {
    const float* pl = part + ((size_t)((ks*6+bh)*NPLANE + qoff))*HW + n;
#pragma unroll
    for (int cc = 0; cc < 8; ++cc) acc[cc] += pl[(size_t)cc*HW];
    den += pl[(size_t)(16 - qoff)*HW];
  }
  // LN1 stats on x
  const float* xp = x + ((size_t)b*CH + c0)*HW + n;
  float xv[8]; float s = 0.f, ssum = 0.f;
#pragma unroll
  for (int cc = 0; cc < 8; ++cc) {
    float vv = xp[(size_t)cc*HW];
    xv[cc] = vv; s += vv; ssum += vv*vv;
  }
  r1[w][lane] = s; r2[w][lane] = ssum;
  __syncthreads();
  float stot = 0.f, sstot = 0.f;
#pragma unroll
  for (int i = 0; i < 6; ++i) { stot += r1[i][lane]; sstot += r2[i][lane]; }
  float mu = stot*(1.f/CH);
  float rs = rsqrtf(sstot*(1.f/CH) - mu*mu + 1e-6f);
  float inv = 1.f / den;
  float yv[8]; float s2 = 0.f, ss2 = 0.f;
#pragma unroll
  for (int cc = 0; cc < 8; ++cc) {
    int c = c0 + cc;
    float xnv = lw1[c]*((xv[cc]-mu)*rs) + lb1[c];
    float y = xv[cc] + xnv*seL[c]*beta[c] + acc[cc]*inv*beta2[c];
    yv[cc] = y; s2 += y; ss2 += y*y;
  }
  r3[w][lane] = s2; r4[w][lane] = ss2;
  __syncthreads();
  float s2t = 0.f, ss2t = 0.f;
#pragma unroll
  for (int i = 0; i < 6; ++i) { s2t += r3[i][lane]; ss2t += r4[i][lane]; }
  float mu2 = s2t*(1.f/CH);
  float rs2 = rsqrtf(ss2t*(1.f/CH) - mu2*mu2 + 1e-6f);
#pragma unroll
  for (int cc = 0; cc < 8; ++cc) {
    int c = c0 + cc;
    xt[c][lane] = lw2[c]*((yv[cc]-mu2)*rs2) + lb2[c];
  }
  __syncthreads();

  // conv4 + gate: wave-uniform rows c0..c0+8 and 48+c0..+8
  float f1[8], f2[8];
#pragma unroll
  for (int j = 0; j < 8; ++j) { f1[j] = b4[c0+j]; f2[j] = b4[CH+c0+j]; }
#pragma unroll 8
  for (int c = 0; c < CH; ++c) {
    float tc = xt[c][lane];
#pragma unroll
    for (int j = 0; j < 8; ++j) {
      f1[j] += w4[(size_t)(c0+j)*CH + c] * tc;
      f2[j] += w4[(size_t)(CH+c0+j)*CH + c] * tc;
    }
  }
#pragma unroll
  for (int j = 0; j < 8; ++j) gt[c0+j][lane] = f1[j]*f2[j];
  __syncthreads();

  // conv5 + residual
  float f5[8];
#pragma unroll
  for (int j = 0; j < 8; ++j) f5[j] = b5[c0+j];
#pragma unroll 8
  for (int c = 0; c < CH; ++c) {
    float gc = gt[c][lane];
#pragma unroll
    for (int j = 0; j < 8; ++j) f5[j] += w5[(size_t)(c0+j)*CH + c] * gc;
  }
  float* op = out + ((size_t)b*CH + c0)*HW + n;
#pragma unroll
  for (int j = 0; j < 8; ++j)
    op[(size_t)j*HW] = yv[j] + f5[j]*gamma[c0+j];
}

extern "C" void kernel_launch(void* const* d_in, const int* in_sizes, int n_in,
                              void* d_out, int out_size, void* d_ws, size_t ws_size,
                              hipStream_t stream) {
  const float* x      = (const float*)d_in[0];
  const float* ln1_w  = (const float*)d_in[1];
  const float* ln1_b  = (const float*)d_in[2];
  const float* qkv_w  = (const float*)d_in[3];
  const float* qkv_b  = (const float*)d_in[4];
  const float* dw_w   = (const float*)d_in[5];
  const float* dw_b   = (const float*)d_in[6];
  const float* temp   = (const float*)d_in[7];
  const float* ca_w1  = (const float*)d_in[8];
  const float* ca_b1  = (const float*)d_in[9];
  const float* ca_w2  = (const float*)d_in[10];
  const float* ca_b2  = (const float*)d_in[11];
  const float* beta   = (const float*)d_in[12];
  const float* beta2  = (const float*)d_in[13];
  const float* ln2_w  = (const float*)d_in[14];
  const float* ln2_b  = (const float*)d_in[15];
  const float* conv4_w= (const float*)d_in[16];
  const float* conv4_b= (const float*)d_in[17];
  const float* conv5_w= (const float*)d_in[18];
  const float* conv5_b= (const float*)d_in[19];
  const float* gamma  = (const float*)d_in[20];

  float* ws   = (float*)d_ws;
  float* bp   = ws + OFF_BP;
  ushort* Qb  = (ushort*)(ws + OFF_QB);
  ushort* Kb  = (ushort*)(ws + OFF_KB);
  ushort* Vtb = (ushort*)(ws + OFF_VT);
  float* qkv1 = ws + OFF_QKV1;
  float* part = ws + OFF_PART;
  float* out  = (float*)d_out;

  k_lnconv<<<256, 256, 0, stream>>>(x, ln1_w, ln1_b, qkv_w, qkv_b, qkv1, bp);
  k_dwprep<<<384, 256, 0, stream>>>(qkv1, dw_w, dw_b, temp, Qb, Kb, Vtb);
  k_attn  <<<768, 256, 0, stream>>>(Qb, Kb, Vtb, part);
  k_tail  <<<128, 384, 0, stream>>>(part, x, ln1_w, ln1_b, bp,
                                    ca_w1, ca_b1, ca_w2, ca_b2,
                                    beta, beta2, ln2_w, ln2_b,
                                    conv4_w, conv4_b, conv5_w, conv5_b,
                                    gamma, out);
}